// Round 1
// baseline (1230.732 us; speedup 1.0000x reference)
//
#include <hip/hip_runtime.h>
#include <math.h>

#define F 128
#define C 300
#define N0_ 409600
#define N1_ 40960
#define N2_ 4096
#define E0_ 409600
#define E1_ 40960

#define BM 64
#define BK 32
#define TPB 256

__device__ __forceinline__ float lrelu(float x) { return x > 0.f ? x : 0.01f * x; }

// out[n][f] = emb[(nid[n]+1)*F+f] + lrelu(sum_c content[n][c]*Wp[f][c] + bp[f])
// Tiles: BM=64 rows x BN=128(=F) cols, BK=32. 256 threads, each owns 8x4 accumulators.
__global__ __launch_bounds__(TPB) void embed_kernel(
    const float* __restrict__ content, const float* __restrict__ Wp,
    const float* __restrict__ bp, const int* __restrict__ nid,
    const float* __restrict__ emb, float* __restrict__ out)
{
  __shared__ float Ast[BK][68];   // A^T tile: [k][r], pad 68 (16B-aligned rows)
  __shared__ float Bs[BK][132];   // B tile: [k][j] = Wp[j][k], pad 132 (16B-aligned)
  const int t = threadIdx.x;
  const int tx = t & 31, ty = t >> 5;
  const int row0 = blockIdx.x * BM;

  float acc[8][4];
#pragma unroll
  for (int i = 0; i < 8; ++i)
#pragma unroll
    for (int j = 0; j < 4; ++j) acc[i][j] = 0.f;

  for (int k0 = 0; k0 < C; k0 += BK) {
    // load A tile (coalesced: consecutive t -> consecutive k within a row)
    for (int idx = t; idx < BM * BK; idx += TPB) {
      int r = idx >> 5, k = idx & 31;
      int kk = k0 + k;
      Ast[k][r] = (kk < C) ? content[(size_t)(row0 + r) * C + kk] : 0.f;
    }
    // load B tile (coalesced along k within each Wp row)
    for (int idx = t; idx < F * BK; idx += TPB) {
      int j = idx >> 5, k = idx & 31;
      int kk = k0 + k;
      Bs[k][j] = (kk < C) ? Wp[(size_t)j * C + kk] : 0.f;
    }
    __syncthreads();
#pragma unroll 4
    for (int kk = 0; kk < BK; ++kk) {
      float4 a0 = *(const float4*)&Ast[kk][ty * 8];
      float4 a1 = *(const float4*)&Ast[kk][ty * 8 + 4];
      float4 b  = *(const float4*)&Bs[kk][tx * 4];
      float a[8] = {a0.x, a0.y, a0.z, a0.w, a1.x, a1.y, a1.z, a1.w};
      float bb[4] = {b.x, b.y, b.z, b.w};
#pragma unroll
      for (int i = 0; i < 8; ++i)
#pragma unroll
        for (int j = 0; j < 4; ++j) acc[i][j] = fmaf(a[i], bb[j], acc[i][j]);
    }
    __syncthreads();
  }

  const float4 bp4 = *(const float4*)&bp[tx * 4];
#pragma unroll
  for (int i = 0; i < 8; ++i) {
    int n = row0 + ty * 8 + i;
    int g = nid[n] + 1;
    const float4 e4 = *(const float4*)&emb[(size_t)g * F + tx * 4];
    float4 o;
    o.x = e4.x + lrelu(acc[i][0] + bp4.x);
    o.y = e4.y + lrelu(acc[i][1] + bp4.y);
    o.z = e4.z + lrelu(acc[i][2] + bp4.z);
    o.w = e4.w + lrelu(acc[i][3] + bp4.w);
    *(float4*)&out[(size_t)n * F + tx * 4] = o;
  }
}

// agg[dst] += hsrc[src]; w[dst] += 1   (atomics; 128 threads per edge)
__global__ __launch_bounds__(TPB) void aggregate_kernel(
    const float* __restrict__ hsrc, const int* __restrict__ src,
    const int* __restrict__ dst, float* __restrict__ agg,
    float* __restrict__ w, int E)
{
  int e = blockIdx.x * 2 + (threadIdx.x >> 7);
  int f = threadIdx.x & 127;
  if (e >= E) return;
  int s = src[e], d = dst[e];
  atomicAdd(&agg[(size_t)d * F + f], hsrc[(size_t)s * F + f]);
  if (f == 0) atomicAdd(&w[d], 1.0f);
}

// x[n] = concat(hs[n], (agg[n]-hs[n])/max(w[n]-1,1));
// out[n] = normalize(lrelu(x[n] @ Wc.T + bc))
__global__ __launch_bounds__(TPB) void conv_kernel(
    const float* __restrict__ hs, const float* __restrict__ agg,
    const float* __restrict__ w, const float* __restrict__ Wc,
    const float* __restrict__ bc, float* __restrict__ out)
{
  __shared__ float Ast[BK][68];
  __shared__ float Bs[BK][132];
  const int t = threadIdx.x;
  const int tx = t & 31, ty = t >> 5;
  const int row0 = blockIdx.x * BM;

  float acc[8][4];
#pragma unroll
  for (int i = 0; i < 8; ++i)
#pragma unroll
    for (int j = 0; j < 4; ++j) acc[i][j] = 0.f;

  for (int k0 = 0; k0 < 2 * F; k0 += BK) {
    for (int idx = t; idx < BM * BK; idx += TPB) {
      int r = idx >> 5, k = idx & 31;
      int n = row0 + r, kk = k0 + k;
      float v;
      if (kk < F) {
        v = hs[(size_t)n * F + kk];
      } else {
        float inv = 1.f / fmaxf(w[n] - 1.f, 1.f);
        v = (agg[(size_t)n * F + kk - F] - hs[(size_t)n * F + kk - F]) * inv;
      }
      Ast[k][r] = v;
    }
    for (int idx = t; idx < F * BK; idx += TPB) {
      int j = idx >> 5, k = idx & 31;
      Bs[k][j] = Wc[(size_t)j * (2 * F) + k0 + k];
    }
    __syncthreads();
#pragma unroll 4
    for (int kk = 0; kk < BK; ++kk) {
      float4 a0 = *(const float4*)&Ast[kk][ty * 8];
      float4 a1 = *(const float4*)&Ast[kk][ty * 8 + 4];
      float4 b  = *(const float4*)&Bs[kk][tx * 4];
      float a[8] = {a0.x, a0.y, a0.z, a0.w, a1.x, a1.y, a1.z, a1.w};
      float bb[4] = {b.x, b.y, b.z, b.w};
#pragma unroll
      for (int i = 0; i < 8; ++i)
#pragma unroll
        for (int j = 0; j < 4; ++j) acc[i][j] = fmaf(a[i], bb[j], acc[i][j]);
    }
    __syncthreads();
  }

  const float4 bc4 = *(const float4*)&bc[tx * 4];
#pragma unroll
  for (int i = 0; i < 8; ++i) {
    float4 x;
    x.x = lrelu(acc[i][0] + bc4.x);
    x.y = lrelu(acc[i][1] + bc4.y);
    x.z = lrelu(acc[i][2] + bc4.z);
    x.w = lrelu(acc[i][3] + bc4.w);
    float ss = x.x * x.x + x.y * x.y + x.z * x.z + x.w * x.w;
#pragma unroll
    for (int m = 16; m >= 1; m >>= 1) ss += __shfl_xor(ss, m, 32);
    float inv = 1.f / fmaxf(sqrtf(ss), 1e-6f);
    int n = row0 + ty * 8 + i;
    float4 o;
    o.x = x.x * inv; o.y = x.y * inv; o.z = x.z * inv; o.w = x.w * inv;
    *(float4*)&out[(size_t)n * F + tx * 4] = o;
  }
}

extern "C" void kernel_launch(void* const* d_in, const int* in_sizes, int n_in,
                              void* d_out, int out_size, void* d_ws, size_t ws_size,
                              hipStream_t stream) {
  const int*   nid0     = (const int*)d_in[0];
  const int*   nid1     = (const int*)d_in[1];
  const int*   nid2     = (const int*)d_in[2];
  const float* content0 = (const float*)d_in[3];
  const float* content1 = (const float*)d_in[4];
  const float* content2 = (const float*)d_in[5];
  const int*   b0s      = (const int*)d_in[6];
  const int*   b0d      = (const int*)d_in[7];
  const int*   b1s      = (const int*)d_in[8];
  const int*   b1d      = (const int*)d_in[9];
  const float* emb      = (const float*)d_in[10];
  const float* Wp0      = (const float*)d_in[11];
  const float* bp0      = (const float*)d_in[12];
  const float* Wp1      = (const float*)d_in[13];
  const float* bp1      = (const float*)d_in[14];
  const float* Wp2      = (const float*)d_in[15];
  const float* bp2      = (const float*)d_in[16];
  const float* Wc0      = (const float*)d_in[17];
  const float* bc0      = (const float*)d_in[18];
  const float* Wc1      = (const float*)d_in[19];
  const float* bc1      = (const float*)d_in[20];

  float* ws   = (float*)d_ws;
  float* h0   = ws;                          // N0*F
  float* h1   = h0 + (size_t)N0_ * F;        // N1*F
  float* h2   = h1 + (size_t)N1_ * F;        // N2*F
  float* agg1 = h2 + (size_t)N2_ * F;        // N1*F
  float* w1   = agg1 + (size_t)N1_ * F;      // N1
  float* agg2 = w1 + N1_;                    // N2*F
  float* w2   = agg2 + (size_t)N2_ * F;      // N2
  float* h1n  = h0;                          // alias: h0 dead after aggregate0

  // zero agg1|w1|agg2|w2 (contiguous)
  hipMemsetAsync(agg1, 0,
                 ((size_t)N1_ * F + N1_ + (size_t)N2_ * F + N2_) * sizeof(float),
                 stream);

  embed_kernel<<<N0_ / BM, TPB, 0, stream>>>(content0, Wp0, bp0, nid0, emb, h0);
  embed_kernel<<<N1_ / BM, TPB, 0, stream>>>(content1, Wp1, bp1, nid1, emb, h1);
  embed_kernel<<<N2_ / BM, TPB, 0, stream>>>(content2, Wp2, bp2, nid2, emb, h2);

  aggregate_kernel<<<E0_ / 2, TPB, 0, stream>>>(h0, b0s, b0d, agg1, w1, E0_);
  conv_kernel<<<N1_ / BM, TPB, 0, stream>>>(h1, agg1, w1, Wc0, bc0, h1n);

  aggregate_kernel<<<E1_ / 2, TPB, 0, stream>>>(h1n, b1s, b1d, agg2, w2, E1_);
  conv_kernel<<<N2_ / BM, TPB, 0, stream>>>(h2, agg2, w2, Wc1, bc1, (float*)d_out);
}

// Round 2
// 647.127 us; speedup vs baseline: 1.9018x; 1.9018x over previous
//
#include <hip/hip_runtime.h>
#include <math.h>

#define F 128
#define C 300
#define CKP 320
#define N0_ 409600
#define N1_ 40960
#define N2_ 4096
#define E0_ 409600
#define E1_ 40960

#define BM 64
#define BK 32
#define TPB 256

typedef unsigned short u16;
typedef __attribute__((ext_vector_type(8))) short short8;
typedef __attribute__((ext_vector_type(8))) unsigned short u16x8;
typedef __attribute__((ext_vector_type(4))) float f32x4;

__device__ __forceinline__ float lrelu(float x) { return x > 0.f ? x : 0.01f * x; }

__device__ __forceinline__ u16 f2bf(float x) {
  union { float f; unsigned int u; } v; v.f = x;
  unsigned int r = (v.u + 0x7fffu + ((v.u >> 16) & 1u)) >> 16;
  return (u16)r;
}

// Wp [F][C] fp32 -> Wpb [F][CKP] bf16 (zero-padded K)
__global__ __launch_bounds__(256) void convert_wp(
    const float* __restrict__ Wp, u16* __restrict__ out)
{
  int i = blockIdx.x * 256 + threadIdx.x;      // over F*CKP
  int f = i / CKP, k = i - f * CKP;
  out[i] = (k < C) ? f2bf(Wp[(size_t)f * C + k]) : (u16)0;
}

// out[n][f] = emb[(nid[n]+1)*F+f] + lrelu(content[n,:] . Wp[f,:] + bp[f])
// MFMA bf16 16x16x32. Block: 128 rows x 128 cols, 4 waves (each 32x128).
__global__ __launch_bounds__(256) void embed_mfma(
    const float* __restrict__ content, const u16* __restrict__ Wpb,
    const float* __restrict__ bp, const int* __restrict__ nid,
    const float* __restrict__ emb, float* __restrict__ out)
{
  __shared__ u16 As[128][32];   // A tile [m][k] bf16, 8KB
  __shared__ u16 Bs[128][32];   // B tile [n][k] bf16, 8KB
  const int t = threadIdx.x;
  const int lane = t & 63, w = t >> 6;
  const int row0 = blockIdx.x * 128;

  f32x4 acc[2][8];
#pragma unroll
  for (int fr = 0; fr < 2; ++fr)
#pragma unroll
    for (int fc = 0; fc < 8; ++fc) {
      acc[fr][fc][0] = 0.f; acc[fr][fc][1] = 0.f;
      acc[fr][fc][2] = 0.f; acc[fr][fc][3] = 0.f;
    }

  const int ar = t >> 1, ah = t & 1;   // A staging: row, 16-float half
  const float* arow = content + (size_t)(row0 + ar) * C;

  for (int k0 = 0; k0 < CKP; k0 += 32) {
    if (k0) __syncthreads();
    // ---- stage A: 16 fp32 -> 16 bf16 per thread ----
    const float4* ap = (const float4*)(arow + k0 + ah * 16);
    float4 f0, f1, f2, f3;
    const float4 z4 = make_float4(0.f, 0.f, 0.f, 0.f);
    if (k0 == 288) {           // K tail: valid k < 300
      if (ah == 0) { f0 = ap[0]; f1 = ap[1]; f2 = ap[2]; f3 = z4; }
      else { f0 = z4; f1 = z4; f2 = z4; f3 = z4; }
    } else {
      f0 = ap[0]; f1 = ap[1]; f2 = ap[2]; f3 = ap[3];
    }
    u16x8 lo, hi;
    lo[0]=f2bf(f0.x); lo[1]=f2bf(f0.y); lo[2]=f2bf(f0.z); lo[3]=f2bf(f0.w);
    lo[4]=f2bf(f1.x); lo[5]=f2bf(f1.y); lo[6]=f2bf(f1.z); lo[7]=f2bf(f1.w);
    hi[0]=f2bf(f2.x); hi[1]=f2bf(f2.y); hi[2]=f2bf(f2.z); hi[3]=f2bf(f2.w);
    hi[4]=f2bf(f3.x); hi[5]=f2bf(f3.y); hi[6]=f2bf(f3.z); hi[7]=f2bf(f3.w);
    *(u16x8*)&As[ar][ah * 16]     = lo;
    *(u16x8*)&As[ar][ah * 16 + 8] = hi;
    // ---- stage B: bf16 copy, 2 x 16B per thread ----
#pragma unroll
    for (int it = 0; it < 2; ++it) {
      int cc = it * 256 + t;                 // chunk of 8 bf16
      int j = cc >> 2, kc = (cc & 3) * 8;
      *(u16x8*)&Bs[j][kc] = *(const u16x8*)&Wpb[(size_t)j * CKP + k0 + kc];
    }
    __syncthreads();

    // ---- fragments + MFMA ----
    const int frow = lane & 15;
    const int kc = (lane >> 4) * 8;
    short8 a0 = *(const short8*)&As[w * 32 + frow][kc];
    short8 a1 = *(const short8*)&As[w * 32 + 16 + frow][kc];
#pragma unroll
    for (int fc = 0; fc < 8; ++fc) {
      short8 b = *(const short8*)&Bs[fc * 16 + frow][kc];
      acc[0][fc] = __builtin_amdgcn_mfma_f32_16x16x32_bf16(a0, b, acc[0][fc], 0, 0, 0);
      acc[1][fc] = __builtin_amdgcn_mfma_f32_16x16x32_bf16(a1, b, acc[1][fc], 0, 0, 0);
    }
  }

  // ---- epilogue: bias + lrelu + emb gather ----
  float bpv[8];
#pragma unroll
  for (int fc = 0; fc < 8; ++fc) bpv[fc] = bp[fc * 16 + (lane & 15)];
#pragma unroll
  for (int fr = 0; fr < 2; ++fr) {
#pragma unroll
    for (int q = 0; q < 4; ++q) {
      int n = row0 + w * 32 + fr * 16 + (lane >> 4) * 4 + q;
      int g = nid[n] + 1;
      const float* erow = emb + (size_t)g * F;
      float* orow = out + (size_t)n * F;
#pragma unroll
      for (int fc = 0; fc < 8; ++fc) {
        int col = fc * 16 + (lane & 15);
        float v = acc[fr][fc][q] + bpv[fc];
        orow[col] = erow[col] + lrelu(v);
      }
    }
  }
}

// agg[dst] += hsrc[src]; w[dst] += 1   (atomics; 128 threads per edge)
__global__ __launch_bounds__(TPB) void aggregate_kernel(
    const float* __restrict__ hsrc, const int* __restrict__ src,
    const int* __restrict__ dst, float* __restrict__ agg,
    float* __restrict__ w, int E)
{
  int e = blockIdx.x * 2 + (threadIdx.x >> 7);
  int f = threadIdx.x & 127;
  if (e >= E) return;
  int s = src[e], d = dst[e];
  atomicAdd(&agg[(size_t)d * F + f], hsrc[(size_t)s * F + f]);
  if (f == 0) atomicAdd(&w[d], 1.0f);
}

// x[n] = concat(hs[n], (agg[n]-hs[n])/max(w[n]-1,1));
// out[n] = normalize(lrelu(x[n] @ Wc.T + bc))
__global__ __launch_bounds__(TPB) void conv_kernel(
    const float* __restrict__ hs, const float* __restrict__ agg,
    const float* __restrict__ w, const float* __restrict__ Wc,
    const float* __restrict__ bc, float* __restrict__ out)
{
  __shared__ float Ast[BK][68];
  __shared__ float Bs[BK][132];
  const int t = threadIdx.x;
  const int tx = t & 31, ty = t >> 5;
  const int row0 = blockIdx.x * BM;

  float acc[8][4];
#pragma unroll
  for (int i = 0; i < 8; ++i)
#pragma unroll
    for (int j = 0; j < 4; ++j) acc[i][j] = 0.f;

  for (int k0 = 0; k0 < 2 * F; k0 += BK) {
    for (int idx = t; idx < BM * BK; idx += TPB) {
      int r = idx >> 5, k = idx & 31;
      int n = row0 + r, kk = k0 + k;
      float v;
      if (kk < F) {
        v = hs[(size_t)n * F + kk];
      } else {
        float inv = 1.f / fmaxf(w[n] - 1.f, 1.f);
        v = (agg[(size_t)n * F + kk - F] - hs[(size_t)n * F + kk - F]) * inv;
      }
      Ast[k][r] = v;
    }
    for (int idx = t; idx < F * BK; idx += TPB) {
      int j = idx >> 5, k = idx & 31;
      Bs[k][j] = Wc[(size_t)j * (2 * F) + k0 + k];
    }
    __syncthreads();
#pragma unroll 4
    for (int kk = 0; kk < BK; ++kk) {
      float4 a0 = *(const float4*)&Ast[kk][ty * 8];
      float4 a1 = *(const float4*)&Ast[kk][ty * 8 + 4];
      float4 b  = *(const float4*)&Bs[kk][tx * 4];
      float a[8] = {a0.x, a0.y, a0.z, a0.w, a1.x, a1.y, a1.z, a1.w};
      float bb[4] = {b.x, b.y, b.z, b.w};
#pragma unroll
      for (int i = 0; i < 8; ++i)
#pragma unroll
        for (int j = 0; j < 4; ++j) acc[i][j] = fmaf(a[i], bb[j], acc[i][j]);
    }
    __syncthreads();
  }

  const float4 bc4 = *(const float4*)&bc[tx * 4];
#pragma unroll
  for (int i = 0; i < 8; ++i) {
    float4 x;
    x.x = lrelu(acc[i][0] + bc4.x);
    x.y = lrelu(acc[i][1] + bc4.y);
    x.z = lrelu(acc[i][2] + bc4.z);
    x.w = lrelu(acc[i][3] + bc4.w);
    float ss = x.x * x.x + x.y * x.y + x.z * x.z + x.w * x.w;
#pragma unroll
    for (int m = 16; m >= 1; m >>= 1) ss += __shfl_xor(ss, m, 32);
    float inv = 1.f / fmaxf(sqrtf(ss), 1e-6f);
    int n = row0 + ty * 8 + i;
    float4 o;
    o.x = x.x * inv; o.y = x.y * inv; o.z = x.z * inv; o.w = x.w * inv;
    *(float4*)&out[(size_t)n * F + tx * 4] = o;
  }
}

extern "C" void kernel_launch(void* const* d_in, const int* in_sizes, int n_in,
                              void* d_out, int out_size, void* d_ws, size_t ws_size,
                              hipStream_t stream) {
  const int*   nid0     = (const int*)d_in[0];
  const int*   nid1     = (const int*)d_in[1];
  const int*   nid2     = (const int*)d_in[2];
  const float* content0 = (const float*)d_in[3];
  const float* content1 = (const float*)d_in[4];
  const float* content2 = (const float*)d_in[5];
  const int*   b0s      = (const int*)d_in[6];
  const int*   b0d      = (const int*)d_in[7];
  const int*   b1s      = (const int*)d_in[8];
  const int*   b1d      = (const int*)d_in[9];
  const float* emb      = (const float*)d_in[10];
  const float* Wp0      = (const float*)d_in[11];
  const float* bp0      = (const float*)d_in[12];
  const float* Wp1      = (const float*)d_in[13];
  const float* bp1      = (const float*)d_in[14];
  const float* Wp2      = (const float*)d_in[15];
  const float* bp2      = (const float*)d_in[16];
  const float* Wc0      = (const float*)d_in[17];
  const float* bc0      = (const float*)d_in[18];
  const float* Wc1      = (const float*)d_in[19];
  const float* bc1      = (const float*)d_in[20];

  float* ws   = (float*)d_ws;
  float* h0   = ws;                          // N0*F
  float* h1   = h0 + (size_t)N0_ * F;        // N1*F
  float* h2   = h1 + (size_t)N1_ * F;        // N2*F
  float* agg1 = h2 + (size_t)N2_ * F;        // N1*F
  float* w1   = agg1 + (size_t)N1_ * F;      // N1
  float* agg2 = w1 + N1_;                    // N2*F
  float* w2   = agg2 + (size_t)N2_ * F;      // N2
  float* h1n  = h0;                          // alias: h0 dead after aggregate0

  // bf16 weights temporarily alias the agg1 region (dead until memset below)
  u16* Wpb0 = (u16*)agg1;
  u16* Wpb1 = Wpb0 + (size_t)F * CKP;
  u16* Wpb2 = Wpb1 + (size_t)F * CKP;

  convert_wp<<<(F * CKP) / 256, 256, 0, stream>>>(Wp0, Wpb0);
  convert_wp<<<(F * CKP) / 256, 256, 0, stream>>>(Wp1, Wpb1);
  convert_wp<<<(F * CKP) / 256, 256, 0, stream>>>(Wp2, Wpb2);

  embed_mfma<<<N0_ / 128, 256, 0, stream>>>(content0, Wpb0, bp0, nid0, emb, h0);
  embed_mfma<<<N1_ / 128, 256, 0, stream>>>(content1, Wpb1, bp1, nid1, emb, h1);
  embed_mfma<<<N2_ / 128, 256, 0, stream>>>(content2, Wpb2, bp2, nid2, emb, h2);

  // zero agg1|w1|agg2|w2 (contiguous) — after embeds, since Wpb aliases agg1
  hipMemsetAsync(agg1, 0,
                 ((size_t)N1_ * F + N1_ + (size_t)N2_ * F + N2_) * sizeof(float),
                 stream);

  aggregate_kernel<<<E0_ / 2, TPB, 0, stream>>>(h0, b0s, b0d, agg1, w1, E0_);
  conv_kernel<<<N1_ / BM, TPB, 0, stream>>>(h1, agg1, w1, Wc0, bc0, h1n);

  aggregate_kernel<<<E1_ / 2, TPB, 0, stream>>>(h1n, b1s, b1d, agg2, w2, E1_);
  conv_kernel<<<N2_ / BM, TPB, 0, stream>>>(h2, agg2, w2, Wc1, bc1, (float*)d_out);
}

// Round 3
// 540.819 us; speedup vs baseline: 2.2757x; 1.1966x over previous
//
#include <hip/hip_runtime.h>
#include <math.h>

#define F 128
#define C 300
#define CKP 320
#define K2F 256
#define N0_ 409600
#define N1_ 40960
#define N2_ 4096
#define E0_ 409600
#define E1_ 40960

#define TPB 256

typedef unsigned short u16;
typedef __attribute__((ext_vector_type(8))) short short8;
typedef __attribute__((ext_vector_type(8))) unsigned short u16x8;
typedef __attribute__((ext_vector_type(4))) float f32x4;

__device__ __forceinline__ float lrelu(float x) { return x > 0.f ? x : 0.01f * x; }

__device__ __forceinline__ u16 f2bf(float x) {
  union { float f; unsigned int u; } v; v.f = x;
  unsigned int r = (v.u + 0x7fffu + ((v.u >> 16) & 1u)) >> 16;
  return (u16)r;
}

__global__ __launch_bounds__(256) void zero_kernel(float4* __restrict__ p, int n4) {
  int i = blockIdx.x * 256 + threadIdx.x;
  if (i < n4) p[i] = make_float4(0.f, 0.f, 0.f, 0.f);
}

// W [F][K] fp32 -> out [F][KP] bf16 (zero-padded K)
__global__ __launch_bounds__(256) void convert_w(
    const float* __restrict__ W, u16* __restrict__ out, int K, int KP)
{
  int i = blockIdx.x * 256 + threadIdx.x;      // over F*KP
  int f = i / KP, k = i - f * KP;
  out[i] = (k < K) ? f2bf(W[(size_t)f * K + k]) : (u16)0;
}

// out[n][f] = emb[(nid[n]+1)*F+f] + lrelu(content[n,:] . Wp[f,:] + bp[f])
// MFMA bf16 16x16x32. Block: 128 rows x 128 cols, 4 waves (each 32x128).
__global__ __launch_bounds__(256) void embed_mfma(
    const float* __restrict__ content, const u16* __restrict__ Wpb,
    const float* __restrict__ bp, const int* __restrict__ nid,
    const float* __restrict__ emb, float* __restrict__ out)
{
  __shared__ u16 As[128][32];
  __shared__ u16 Bs[128][32];
  const int t = threadIdx.x;
  const int lane = t & 63, w = t >> 6;
  const int row0 = blockIdx.x * 128;

  f32x4 acc[2][8];
#pragma unroll
  for (int fr = 0; fr < 2; ++fr)
#pragma unroll
    for (int fc = 0; fc < 8; ++fc) {
      acc[fr][fc][0] = 0.f; acc[fr][fc][1] = 0.f;
      acc[fr][fc][2] = 0.f; acc[fr][fc][3] = 0.f;
    }

  const int ar = t >> 1, ah = t & 1;
  const float* arow = content + (size_t)(row0 + ar) * C;

  for (int k0 = 0; k0 < CKP; k0 += 32) {
    if (k0) __syncthreads();
    const float4* ap = (const float4*)(arow + k0 + ah * 16);
    float4 f0, f1, f2, f3;
    const float4 z4 = make_float4(0.f, 0.f, 0.f, 0.f);
    if (k0 == 288) {
      if (ah == 0) { f0 = ap[0]; f1 = ap[1]; f2 = ap[2]; f3 = z4; }
      else { f0 = z4; f1 = z4; f2 = z4; f3 = z4; }
    } else {
      f0 = ap[0]; f1 = ap[1]; f2 = ap[2]; f3 = ap[3];
    }
    u16x8 lo, hi;
    lo[0]=f2bf(f0.x); lo[1]=f2bf(f0.y); lo[2]=f2bf(f0.z); lo[3]=f2bf(f0.w);
    lo[4]=f2bf(f1.x); lo[5]=f2bf(f1.y); lo[6]=f2bf(f1.z); lo[7]=f2bf(f1.w);
    hi[0]=f2bf(f2.x); hi[1]=f2bf(f2.y); hi[2]=f2bf(f2.z); hi[3]=f2bf(f2.w);
    hi[4]=f2bf(f3.x); hi[5]=f2bf(f3.y); hi[6]=f2bf(f3.z); hi[7]=f2bf(f3.w);
    *(u16x8*)&As[ar][ah * 16]     = lo;
    *(u16x8*)&As[ar][ah * 16 + 8] = hi;
#pragma unroll
    for (int it = 0; it < 2; ++it) {
      int cc = it * 256 + t;
      int j = cc >> 2, kc = (cc & 3) * 8;
      *(u16x8*)&Bs[j][kc] = *(const u16x8*)&Wpb[(size_t)j * CKP + k0 + kc];
    }
    __syncthreads();

    const int frow = lane & 15;
    const int kc = (lane >> 4) * 8;
    short8 a0 = *(const short8*)&As[w * 32 + frow][kc];
    short8 a1 = *(const short8*)&As[w * 32 + 16 + frow][kc];
#pragma unroll
    for (int fc = 0; fc < 8; ++fc) {
      short8 b = *(const short8*)&Bs[fc * 16 + frow][kc];
      acc[0][fc] = __builtin_amdgcn_mfma_f32_16x16x32_bf16(a0, b, acc[0][fc], 0, 0, 0);
      acc[1][fc] = __builtin_amdgcn_mfma_f32_16x16x32_bf16(a1, b, acc[1][fc], 0, 0, 0);
    }
  }

  float bpv[8];
#pragma unroll
  for (int fc = 0; fc < 8; ++fc) bpv[fc] = bp[fc * 16 + (lane & 15)];
#pragma unroll
  for (int fr = 0; fr < 2; ++fr) {
#pragma unroll
    for (int q = 0; q < 4; ++q) {
      int n = row0 + w * 32 + fr * 16 + (lane >> 4) * 4 + q;
      int g = nid[n] + 1;
      const float* erow = emb + (size_t)g * F;
      float* orow = out + (size_t)n * F;
#pragma unroll
      for (int fc = 0; fc < 8; ++fc) {
        int col = fc * 16 + (lane & 15);
        float v = acc[fr][fc][q] + bpv[fc];
        orow[col] = erow[col] + lrelu(v);
      }
    }
  }
}

// agg[dst] += hsrc[src]; w[dst] += 1   (atomics; 128 threads per edge)
__global__ __launch_bounds__(TPB) void aggregate_kernel(
    const float* __restrict__ hsrc, const int* __restrict__ src,
    const int* __restrict__ dst, float* __restrict__ agg,
    float* __restrict__ w, int E)
{
  int e = blockIdx.x * 2 + (threadIdx.x >> 7);
  int f = threadIdx.x & 127;
  if (e >= E) return;
  int s = src[e], d = dst[e];
  atomicAdd(&agg[(size_t)d * F + f], hsrc[(size_t)s * F + f]);
  if (f == 0) atomicAdd(&w[d], 1.0f);
}

// x[n] = concat(hs[n], (agg[n]-hs[n])/max(w[n]-1,1))  (K=256)
// out[n] = normalize(lrelu(x[n] @ Wc.T + bc))
// MFMA bf16, block 128 rows x 128 cols, 4 waves.
__global__ __launch_bounds__(256) void conv_mfma(
    const float* __restrict__ hs, const float* __restrict__ agg,
    const float* __restrict__ wdeg, const u16* __restrict__ Wcb,
    const float* __restrict__ bc, float* __restrict__ out)
{
  __shared__ u16 As[128][32];
  __shared__ u16 Bs[128][32];
  const int t = threadIdx.x;
  const int lane = t & 63, w = t >> 6;
  const int row0 = blockIdx.x * 128;

  f32x4 acc[2][8];
#pragma unroll
  for (int fr = 0; fr < 2; ++fr)
#pragma unroll
    for (int fc = 0; fc < 8; ++fc) {
      acc[fr][fc][0] = 0.f; acc[fr][fc][1] = 0.f;
      acc[fr][fc][2] = 0.f; acc[fr][fc][3] = 0.f;
    }

  const int ar = t >> 1, ah = t & 1;
  const int arow_n = row0 + ar;
  const float* hrow = hs + (size_t)arow_n * F;
  const float* grow = agg + (size_t)arow_n * F;
  const float inv = 1.f / fmaxf(wdeg[arow_n] - 1.f, 1.f);

  for (int k0 = 0; k0 < K2F; k0 += 32) {
    if (k0) __syncthreads();
    // ---- stage A: 16 values -> bf16 ----
    float4 f0, f1, f2, f3;
    int kk = k0 + ah * 16;
    if (kk < F) {
      const float4* hp = (const float4*)(hrow + kk);
      f0 = hp[0]; f1 = hp[1]; f2 = hp[2]; f3 = hp[3];
    } else {
      const float4* hp = (const float4*)(hrow + kk - F);
      const float4* gp = (const float4*)(grow + kk - F);
#pragma unroll
      for (int q = 0; q < 4; ++q) {
        float4 h4 = hp[q], g4 = gp[q];
        float4 r;
        r.x = (g4.x - h4.x) * inv; r.y = (g4.y - h4.y) * inv;
        r.z = (g4.z - h4.z) * inv; r.w = (g4.w - h4.w) * inv;
        if (q == 0) f0 = r; else if (q == 1) f1 = r; else if (q == 2) f2 = r; else f3 = r;
      }
    }
    u16x8 lo, hi;
    lo[0]=f2bf(f0.x); lo[1]=f2bf(f0.y); lo[2]=f2bf(f0.z); lo[3]=f2bf(f0.w);
    lo[4]=f2bf(f1.x); lo[5]=f2bf(f1.y); lo[6]=f2bf(f1.z); lo[7]=f2bf(f1.w);
    hi[0]=f2bf(f2.x); hi[1]=f2bf(f2.y); hi[2]=f2bf(f2.z); hi[3]=f2bf(f2.w);
    hi[4]=f2bf(f3.x); hi[5]=f2bf(f3.y); hi[6]=f2bf(f3.z); hi[7]=f2bf(f3.w);
    *(u16x8*)&As[ar][ah * 16]     = lo;
    *(u16x8*)&As[ar][ah * 16 + 8] = hi;
    // ---- stage B ----
#pragma unroll
    for (int it = 0; it < 2; ++it) {
      int cc = it * 256 + t;
      int j = cc >> 2, kc = (cc & 3) * 8;
      *(u16x8*)&Bs[j][kc] = *(const u16x8*)&Wcb[(size_t)j * K2F + k0 + kc];
    }
    __syncthreads();

    const int frow = lane & 15;
    const int kc = (lane >> 4) * 8;
    short8 a0 = *(const short8*)&As[w * 32 + frow][kc];
    short8 a1 = *(const short8*)&As[w * 32 + 16 + frow][kc];
#pragma unroll
    for (int fc = 0; fc < 8; ++fc) {
      short8 b = *(const short8*)&Bs[fc * 16 + frow][kc];
      acc[0][fc] = __builtin_amdgcn_mfma_f32_16x16x32_bf16(a0, b, acc[0][fc], 0, 0, 0);
      acc[1][fc] = __builtin_amdgcn_mfma_f32_16x16x32_bf16(a1, b, acc[1][fc], 0, 0, 0);
    }
  }

  float bcv[8];
#pragma unroll
  for (int fc = 0; fc < 8; ++fc) bcv[fc] = bc[fc * 16 + (lane & 15)];
#pragma unroll
  for (int fr = 0; fr < 2; ++fr) {
#pragma unroll
    for (int q = 0; q < 4; ++q) {
      float x[8];
      float ss = 0.f;
#pragma unroll
      for (int fc = 0; fc < 8; ++fc) {
        x[fc] = lrelu(acc[fr][fc][q] + bcv[fc]);
        ss += x[fc] * x[fc];
      }
      // reduce across the 16 lanes that share this row (lane bits 0-3)
#pragma unroll
      for (int m = 8; m >= 1; m >>= 1) ss += __shfl_xor(ss, m, 64);
      float nrm = 1.f / fmaxf(sqrtf(ss), 1e-6f);
      int n = row0 + w * 32 + fr * 16 + (lane >> 4) * 4 + q;
      float* orow = out + (size_t)n * F;
#pragma unroll
      for (int fc = 0; fc < 8; ++fc) {
        int col = fc * 16 + (lane & 15);
        orow[col] = x[fc] * nrm;
      }
    }
  }
}

extern "C" void kernel_launch(void* const* d_in, const int* in_sizes, int n_in,
                              void* d_out, int out_size, void* d_ws, size_t ws_size,
                              hipStream_t stream) {
  const int*   nid0     = (const int*)d_in[0];
  const int*   nid1     = (const int*)d_in[1];
  const int*   nid2     = (const int*)d_in[2];
  const float* content0 = (const float*)d_in[3];
  const float* content1 = (const float*)d_in[4];
  const float* content2 = (const float*)d_in[5];
  const int*   b0s      = (const int*)d_in[6];
  const int*   b0d      = (const int*)d_in[7];
  const int*   b1s      = (const int*)d_in[8];
  const int*   b1d      = (const int*)d_in[9];
  const float* emb      = (const float*)d_in[10];
  const float* Wp0      = (const float*)d_in[11];
  const float* bp0      = (const float*)d_in[12];
  const float* Wp1      = (const float*)d_in[13];
  const float* bp1      = (const float*)d_in[14];
  const float* Wp2      = (const float*)d_in[15];
  const float* bp2      = (const float*)d_in[16];
  const float* Wc0      = (const float*)d_in[17];
  const float* bc0      = (const float*)d_in[18];
  const float* Wc1      = (const float*)d_in[19];
  const float* bc1      = (const float*)d_in[20];

  float* ws   = (float*)d_ws;
  float* h0   = ws;                          // N0*F
  float* h1   = h0 + (size_t)N0_ * F;        // N1*F
  float* h2   = h1 + (size_t)N1_ * F;        // N2*F
  float* agg1 = h2 + (size_t)N2_ * F;        // N1*F   } contiguous zero region
  float* w1   = agg1 + (size_t)N1_ * F;      // N1     }
  float* agg2 = w1 + N1_;                    // N2*F   }
  float* w2   = agg2 + (size_t)N2_ * F;      // N2     }
  float* wend = w2 + N2_;
  u16* Wpb0 = (u16*)wend;                    // F*CKP bf16 each
  u16* Wpb1 = Wpb0 + (size_t)F * CKP;
  u16* Wpb2 = Wpb1 + (size_t)F * CKP;
  u16* Wcb0 = Wpb2 + (size_t)F * CKP;        // F*256 bf16 each
  u16* Wcb1 = Wcb0 + (size_t)F * K2F;
  float* h1n = h0;                           // alias: h0 dead after aggregate0

  const int zeroN = N1_ * F + N1_ + N2_ * F + N2_;   // floats, 16B-aligned
  zero_kernel<<<(zeroN / 4 + 255) / 256, 256, 0, stream>>>((float4*)agg1, zeroN / 4);

  convert_w<<<(F * CKP) / 256, 256, 0, stream>>>(Wp0, Wpb0, C, CKP);
  convert_w<<<(F * CKP) / 256, 256, 0, stream>>>(Wp1, Wpb1, C, CKP);
  convert_w<<<(F * CKP) / 256, 256, 0, stream>>>(Wp2, Wpb2, C, CKP);
  convert_w<<<(F * K2F) / 256, 256, 0, stream>>>(Wc0, Wcb0, K2F, K2F);
  convert_w<<<(F * K2F) / 256, 256, 0, stream>>>(Wc1, Wcb1, K2F, K2F);

  embed_mfma<<<N0_ / 128, 256, 0, stream>>>(content0, Wpb0, bp0, nid0, emb, h0);
  embed_mfma<<<N1_ / 128, 256, 0, stream>>>(content1, Wpb1, bp1, nid1, emb, h1);
  embed_mfma<<<N2_ / 128, 256, 0, stream>>>(content2, Wpb2, bp2, nid2, emb, h2);

  aggregate_kernel<<<E0_ / 2, TPB, 0, stream>>>(h0, b0s, b0d, agg1, w1, E0_);
  conv_mfma<<<N1_ / 128, 256, 0, stream>>>(h1, agg1, w1, Wcb0, bc0, h1n);

  aggregate_kernel<<<E1_ / 2, TPB, 0, stream>>>(h1n, b1s, b1d, agg2, w2, E1_);
  conv_mfma<<<N2_ / 128, 256, 0, stream>>>(h2, agg2, w2, Wcb1, bc1, (float*)d_out);
}

// Round 4
// 494.872 us; speedup vs baseline: 2.4870x; 1.0928x over previous
//
#include <hip/hip_runtime.h>
#include <math.h>

#define F 128
#define C 300
#define CKP 320
#define K2F 256
#define N0_ 409600
#define N1_ 40960
#define N2_ 4096
#define E0_ 409600
#define E1_ 40960

typedef unsigned short u16;
typedef __attribute__((ext_vector_type(8))) short short8;
typedef __attribute__((ext_vector_type(8))) unsigned short u16x8;
typedef __attribute__((ext_vector_type(4))) float f32x4;

__device__ __forceinline__ float lrelu(float x) { return x > 0.f ? x : 0.01f * x; }

__device__ __forceinline__ u16 f2bf(float x) {
  union { float f; unsigned int u; } v; v.f = x;
  unsigned int r = (v.u + 0x7fffu + ((v.u >> 16) & 1u)) >> 16;
  return (u16)r;
}

__global__ __launch_bounds__(256) void zero_kernel(float4* __restrict__ p, int n4) {
  int i = blockIdx.x * 256 + threadIdx.x;
  if (i < n4) p[i] = make_float4(0.f, 0.f, 0.f, 0.f);
}

// W [F][K] fp32 -> out [F][KP] bf16 (zero-padded K)
__global__ __launch_bounds__(256) void convert_w(
    const float* __restrict__ W, u16* __restrict__ out, int K, int KP)
{
  int i = blockIdx.x * 256 + threadIdx.x;
  int f = i / KP, k = i - f * KP;
  out[i] = (k < K) ? f2bf(W[(size_t)f * K + k]) : (u16)0;
}

// ---------------- CSR build ----------------
__global__ __launch_bounds__(256) void hist_kernel(
    const int* __restrict__ dst, int* __restrict__ deg, int E)
{
  int e = blockIdx.x * 256 + threadIdx.x;
  if (e < E) atomicAdd(&deg[dst[e]], 1);
}

// single-block exclusive scan of deg[0..N) -> off[0..N], pos[0..N) ; off[N]=total
__global__ __launch_bounds__(1024) void scan_kernel(
    const int* __restrict__ deg, int* __restrict__ off, int* __restrict__ pos, int N)
{
  __shared__ int wsum[16];
  __shared__ int tot_s;
  __shared__ int carry_s;
  const int t = threadIdx.x, lane = t & 63, wid = t >> 6;
  if (t == 0) carry_s = 0;
  __syncthreads();
  for (int base = 0; base < N; base += 1024) {
    int cbase = carry_s;
    int x = (base + t < N) ? deg[base + t] : 0;
    int inc = x;
#pragma unroll
    for (int s = 1; s < 64; s <<= 1) {
      int v = __shfl_up(inc, s, 64);
      if (lane >= s) inc += v;
    }
    if (lane == 63) wsum[wid] = inc;
    __syncthreads();
    if (t == 0) {
      int run = 0;
#pragma unroll
      for (int i = 0; i < 16; ++i) { int v = wsum[i]; wsum[i] = run; run += v; }
      tot_s = run;
    }
    __syncthreads();
    int ex = cbase + wsum[wid] + (inc - x);
    if (base + t < N) { off[base + t] = ex; pos[base + t] = ex; }
    if (t == 0) carry_s = cbase + tot_s;
    __syncthreads();
  }
  if (t == 0) off[N] = carry_s;
}

__global__ __launch_bounds__(256) void scatter_kernel(
    const int* __restrict__ src, const int* __restrict__ dst,
    int* __restrict__ pos, int* __restrict__ csr, int E)
{
  int e = blockIdx.x * 256 + threadIdx.x;
  if (e < E) {
    int slot = atomicAdd(&pos[dst[e]], 1);
    csr[slot] = src[e];
  }
}

// agg[d][f] = sum_{j in off[d]..off[d+1]} hsrc[csr[j]][f]   (no atomics)
__global__ __launch_bounds__(256) void gather_agg(
    const float* __restrict__ hsrc, const int* __restrict__ csr,
    const int* __restrict__ off, float* __restrict__ agg)
{
  int d = blockIdx.x * 2 + (threadIdx.x >> 7);
  int f = threadIdx.x & 127;
  int st = off[d], en = off[d + 1];
  float s = 0.f;
  int j = st;
  for (; j + 1 < en; j += 2) {
    float a = hsrc[(size_t)csr[j] * F + f];
    float b = hsrc[(size_t)csr[j + 1] * F + f];
    s += a + b;
  }
  if (j < en) s += hsrc[(size_t)csr[j] * F + f];
  agg[(size_t)d * F + f] = s;
}

// out[n][f] = emb[(nid[n]+1)*F+f] + lrelu(content[n,:] . Wp[f,:] + bp[f])
__global__ __launch_bounds__(256) void embed_mfma(
    const float* __restrict__ content, const u16* __restrict__ Wpb,
    const float* __restrict__ bp, const int* __restrict__ nid,
    const float* __restrict__ emb, float* __restrict__ out)
{
  __shared__ u16 As[128][32];
  __shared__ u16 Bs[128][32];
  const int t = threadIdx.x;
  const int lane = t & 63, w = t >> 6;
  const int row0 = blockIdx.x * 128;

  f32x4 acc[2][8];
#pragma unroll
  for (int fr = 0; fr < 2; ++fr)
#pragma unroll
    for (int fc = 0; fc < 8; ++fc) {
      acc[fr][fc][0] = 0.f; acc[fr][fc][1] = 0.f;
      acc[fr][fc][2] = 0.f; acc[fr][fc][3] = 0.f;
    }

  const int ar = t >> 1, ah = t & 1;
  const float* arow = content + (size_t)(row0 + ar) * C;

  for (int k0 = 0; k0 < CKP; k0 += 32) {
    if (k0) __syncthreads();
    const float4* ap = (const float4*)(arow + k0 + ah * 16);
    float4 f0, f1, f2, f3;
    const float4 z4 = make_float4(0.f, 0.f, 0.f, 0.f);
    if (k0 == 288) {
      if (ah == 0) { f0 = ap[0]; f1 = ap[1]; f2 = ap[2]; f3 = z4; }
      else { f0 = z4; f1 = z4; f2 = z4; f3 = z4; }
    } else {
      f0 = ap[0]; f1 = ap[1]; f2 = ap[2]; f3 = ap[3];
    }
    u16x8 lo, hi;
    lo[0]=f2bf(f0.x); lo[1]=f2bf(f0.y); lo[2]=f2bf(f0.z); lo[3]=f2bf(f0.w);
    lo[4]=f2bf(f1.x); lo[5]=f2bf(f1.y); lo[6]=f2bf(f1.z); lo[7]=f2bf(f1.w);
    hi[0]=f2bf(f2.x); hi[1]=f2bf(f2.y); hi[2]=f2bf(f2.z); hi[3]=f2bf(f2.w);
    hi[4]=f2bf(f3.x); hi[5]=f2bf(f3.y); hi[6]=f2bf(f3.z); hi[7]=f2bf(f3.w);
    *(u16x8*)&As[ar][ah * 16]     = lo;
    *(u16x8*)&As[ar][ah * 16 + 8] = hi;
#pragma unroll
    for (int it = 0; it < 2; ++it) {
      int cc = it * 256 + t;
      int j = cc >> 2, kc = (cc & 3) * 8;
      *(u16x8*)&Bs[j][kc] = *(const u16x8*)&Wpb[(size_t)j * CKP + k0 + kc];
    }
    __syncthreads();

    const int frow = lane & 15;
    const int kc = (lane >> 4) * 8;
    short8 a0 = *(const short8*)&As[w * 32 + frow][kc];
    short8 a1 = *(const short8*)&As[w * 32 + 16 + frow][kc];
#pragma unroll
    for (int fc = 0; fc < 8; ++fc) {
      short8 b = *(const short8*)&Bs[fc * 16 + frow][kc];
      acc[0][fc] = __builtin_amdgcn_mfma_f32_16x16x32_bf16(a0, b, acc[0][fc], 0, 0, 0);
      acc[1][fc] = __builtin_amdgcn_mfma_f32_16x16x32_bf16(a1, b, acc[1][fc], 0, 0, 0);
    }
  }

  float bpv[8];
#pragma unroll
  for (int fc = 0; fc < 8; ++fc) bpv[fc] = bp[fc * 16 + (lane & 15)];
#pragma unroll
  for (int fr = 0; fr < 2; ++fr) {
#pragma unroll
    for (int q = 0; q < 4; ++q) {
      int n = row0 + w * 32 + fr * 16 + (lane >> 4) * 4 + q;
      int g = nid[n] + 1;
      const float* erow = emb + (size_t)g * F;
      float* orow = out + (size_t)n * F;
#pragma unroll
      for (int fc = 0; fc < 8; ++fc) {
        int col = fc * 16 + (lane & 15);
        float v = acc[fr][fc][q] + bpv[fc];
        orow[col] = erow[col] + lrelu(v);
      }
    }
  }
}

// x[n] = concat(hs[n], (agg[n]-hs[n])/max(deg[n]-1,1))  (K=256)
// out[n] = normalize(lrelu(x[n] @ Wc.T + bc))
__global__ __launch_bounds__(256) void conv_mfma(
    const float* __restrict__ hs, const float* __restrict__ agg,
    const int* __restrict__ deg, const u16* __restrict__ Wcb,
    const float* __restrict__ bc, float* __restrict__ out)
{
  __shared__ u16 As[128][32];
  __shared__ u16 Bs[128][32];
  const int t = threadIdx.x;
  const int lane = t & 63, w = t >> 6;
  const int row0 = blockIdx.x * 128;

  f32x4 acc[2][8];
#pragma unroll
  for (int fr = 0; fr < 2; ++fr)
#pragma unroll
    for (int fc = 0; fc < 8; ++fc) {
      acc[fr][fc][0] = 0.f; acc[fr][fc][1] = 0.f;
      acc[fr][fc][2] = 0.f; acc[fr][fc][3] = 0.f;
    }

  const int ar = t >> 1, ah = t & 1;
  const int arow_n = row0 + ar;
  const float* hrow = hs + (size_t)arow_n * F;
  const float* grow = agg + (size_t)arow_n * F;
  const float inv = 1.f / fmaxf((float)deg[arow_n] - 1.f, 1.f);

  for (int k0 = 0; k0 < K2F; k0 += 32) {
    if (k0) __syncthreads();
    float4 f0, f1, f2, f3;
    int kk = k0 + ah * 16;
    if (kk < F) {
      const float4* hp = (const float4*)(hrow + kk);
      f0 = hp[0]; f1 = hp[1]; f2 = hp[2]; f3 = hp[3];
    } else {
      const float4* hp = (const float4*)(hrow + kk - F);
      const float4* gp = (const float4*)(grow + kk - F);
#pragma unroll
      for (int q = 0; q < 4; ++q) {
        float4 h4 = hp[q], g4 = gp[q];
        float4 r;
        r.x = (g4.x - h4.x) * inv; r.y = (g4.y - h4.y) * inv;
        r.z = (g4.z - h4.z) * inv; r.w = (g4.w - h4.w) * inv;
        if (q == 0) f0 = r; else if (q == 1) f1 = r; else if (q == 2) f2 = r; else f3 = r;
      }
    }
    u16x8 lo, hi;
    lo[0]=f2bf(f0.x); lo[1]=f2bf(f0.y); lo[2]=f2bf(f0.z); lo[3]=f2bf(f0.w);
    lo[4]=f2bf(f1.x); lo[5]=f2bf(f1.y); lo[6]=f2bf(f1.z); lo[7]=f2bf(f1.w);
    hi[0]=f2bf(f2.x); hi[1]=f2bf(f2.y); hi[2]=f2bf(f2.z); hi[3]=f2bf(f2.w);
    hi[4]=f2bf(f3.x); hi[5]=f2bf(f3.y); hi[6]=f2bf(f3.z); hi[7]=f2bf(f3.w);
    *(u16x8*)&As[ar][ah * 16]     = lo;
    *(u16x8*)&As[ar][ah * 16 + 8] = hi;
#pragma unroll
    for (int it = 0; it < 2; ++it) {
      int cc = it * 256 + t;
      int j = cc >> 2, kc = (cc & 3) * 8;
      *(u16x8*)&Bs[j][kc] = *(const u16x8*)&Wcb[(size_t)j * K2F + k0 + kc];
    }
    __syncthreads();

    const int frow = lane & 15;
    const int kc = (lane >> 4) * 8;
    short8 a0 = *(const short8*)&As[w * 32 + frow][kc];
    short8 a1 = *(const short8*)&As[w * 32 + 16 + frow][kc];
#pragma unroll
    for (int fc = 0; fc < 8; ++fc) {
      short8 b = *(const short8*)&Bs[fc * 16 + frow][kc];
      acc[0][fc] = __builtin_amdgcn_mfma_f32_16x16x32_bf16(a0, b, acc[0][fc], 0, 0, 0);
      acc[1][fc] = __builtin_amdgcn_mfma_f32_16x16x32_bf16(a1, b, acc[1][fc], 0, 0, 0);
    }
  }

  float bcv[8];
#pragma unroll
  for (int fc = 0; fc < 8; ++fc) bcv[fc] = bc[fc * 16 + (lane & 15)];
#pragma unroll
  for (int fr = 0; fr < 2; ++fr) {
#pragma unroll
    for (int q = 0; q < 4; ++q) {
      float x[8];
      float ss = 0.f;
#pragma unroll
      for (int fc = 0; fc < 8; ++fc) {
        x[fc] = lrelu(acc[fr][fc][q] + bcv[fc]);
        ss += x[fc] * x[fc];
      }
#pragma unroll
      for (int m = 8; m >= 1; m >>= 1) ss += __shfl_xor(ss, m, 64);
      float nrm = 1.f / fmaxf(sqrtf(ss), 1e-6f);
      int n = row0 + w * 32 + fr * 16 + (lane >> 4) * 4 + q;
      float* orow = out + (size_t)n * F;
#pragma unroll
      for (int fc = 0; fc < 8; ++fc) {
        int col = fc * 16 + (lane & 15);
        orow[col] = x[fc] * nrm;
      }
    }
  }
}

extern "C" void kernel_launch(void* const* d_in, const int* in_sizes, int n_in,
                              void* d_out, int out_size, void* d_ws, size_t ws_size,
                              hipStream_t stream) {
  const int*   nid0     = (const int*)d_in[0];
  const int*   nid1     = (const int*)d_in[1];
  const int*   nid2     = (const int*)d_in[2];
  const float* content0 = (const float*)d_in[3];
  const float* content1 = (const float*)d_in[4];
  const float* content2 = (const float*)d_in[5];
  const int*   b0s      = (const int*)d_in[6];
  const int*   b0d      = (const int*)d_in[7];
  const int*   b1s      = (const int*)d_in[8];
  const int*   b1d      = (const int*)d_in[9];
  const float* emb      = (const float*)d_in[10];
  const float* Wp0      = (const float*)d_in[11];
  const float* bp0      = (const float*)d_in[12];
  const float* Wp1      = (const float*)d_in[13];
  const float* bp1      = (const float*)d_in[14];
  const float* Wp2      = (const float*)d_in[15];
  const float* bp2      = (const float*)d_in[16];
  const float* Wc0      = (const float*)d_in[17];
  const float* bc0      = (const float*)d_in[18];
  const float* Wc1      = (const float*)d_in[19];
  const float* bc1      = (const float*)d_in[20];

  float* ws   = (float*)d_ws;
  float* h0   = ws;                          // N0*F
  float* h1   = h0 + (size_t)N0_ * F;        // N1*F
  float* h2   = h1 + (size_t)N1_ * F;        // N2*F
  float* agg1 = h2 + (size_t)N2_ * F;        // N1*F
  float* agg2 = agg1 + (size_t)N1_ * F;      // N2*F
  float* fend = agg2 + (size_t)N2_ * F;
  u16* Wpb0 = (u16*)fend;                    // F*CKP bf16 each
  u16* Wpb1 = Wpb0 + (size_t)F * CKP;
  u16* Wpb2 = Wpb1 + (size_t)F * CKP;
  u16* Wcb0 = Wpb2 + (size_t)F * CKP;        // F*K2F bf16 each
  u16* Wcb1 = Wcb0 + (size_t)F * K2F;
  int* deg0 = (int*)(Wcb1 + (size_t)F * K2F);  // N1  } zeroed together
  int* deg1 = deg0 + N1_;                      // N2  }
  int* off0 = deg1 + N2_;                      // N1+4
  int* pos0 = off0 + N1_ + 4;                  // N1+4
  int* off1 = pos0 + N1_ + 4;                  // N2+4
  int* pos1 = off1 + N2_ + 4;                  // N2+4
  int* csr0 = pos1 + N2_ + 4;                  // E0
  int* csr1 = csr0 + E0_;                      // E1
  float* h1n = h0;                             // alias: h0 dead after gather0

  // zero deg0|deg1 (contiguous ints, 16B-aligned)
  const int zn4 = (N1_ + N2_) / 4;
  zero_kernel<<<(zn4 + 255) / 256, 256, 0, stream>>>((float4*)deg0, zn4);

  // CSR build for both blocks
  hist_kernel<<<(E0_ + 255) / 256, 256, 0, stream>>>(b0d, deg0, E0_);
  hist_kernel<<<(E1_ + 255) / 256, 256, 0, stream>>>(b1d, deg1, E1_);
  scan_kernel<<<1, 1024, 0, stream>>>(deg0, off0, pos0, N1_);
  scan_kernel<<<1, 1024, 0, stream>>>(deg1, off1, pos1, N2_);
  scatter_kernel<<<(E0_ + 255) / 256, 256, 0, stream>>>(b0s, b0d, pos0, csr0, E0_);
  scatter_kernel<<<(E1_ + 255) / 256, 256, 0, stream>>>(b1s, b1d, pos1, csr1, E1_);

  // weight conversion
  convert_w<<<(F * CKP) / 256, 256, 0, stream>>>(Wp0, Wpb0, C, CKP);
  convert_w<<<(F * CKP) / 256, 256, 0, stream>>>(Wp1, Wpb1, C, CKP);
  convert_w<<<(F * CKP) / 256, 256, 0, stream>>>(Wp2, Wpb2, C, CKP);
  convert_w<<<(F * K2F) / 256, 256, 0, stream>>>(Wc0, Wcb0, K2F, K2F);
  convert_w<<<(F * K2F) / 256, 256, 0, stream>>>(Wc1, Wcb1, K2F, K2F);

  embed_mfma<<<N0_ / 128, 256, 0, stream>>>(content0, Wpb0, bp0, nid0, emb, h0);
  embed_mfma<<<N1_ / 128, 256, 0, stream>>>(content1, Wpb1, bp1, nid1, emb, h1);
  embed_mfma<<<N2_ / 128, 256, 0, stream>>>(content2, Wpb2, bp2, nid2, emb, h2);

  gather_agg<<<N1_ / 2, 256, 0, stream>>>(h0, csr0, off0, agg1);
  conv_mfma<<<N1_ / 128, 256, 0, stream>>>(h1, agg1, deg0, Wcb0, bc0, h1n);

  gather_agg<<<N2_ / 2, 256, 0, stream>>>(h1n, csr1, off1, agg2);
  conv_mfma<<<N2_ / 128, 256, 0, stream>>>(h2, agg2, deg1, Wcb1, bc1, (float*)d_out);
}

// Round 5
// 420.577 us; speedup vs baseline: 2.9263x; 1.1766x over previous
//
#include <hip/hip_runtime.h>
#include <hip/hip_bf16.h>
#include <math.h>

#define F 128
#define C 300
#define CKP 320
#define K2F 256
#define N0_ 409600
#define N1_ 40960
#define N2_ 4096
#define E0_ 409600
#define E1_ 40960
#define CAP 64
#define LDA 40   // u16 row stride of LDS tiles (80B) -> ~conflict-free b128 frag reads

typedef unsigned short u16;
typedef unsigned int u32;
typedef __attribute__((ext_vector_type(8))) short short8;
typedef __attribute__((ext_vector_type(8))) unsigned short u16x8;
typedef __attribute__((ext_vector_type(4))) float f32x4;

__device__ __forceinline__ float lrelu(float x) { return x > 0.f ? x : 0.01f * x; }

__device__ __forceinline__ u16 f2bf(float x) {
  __hip_bfloat16 h = __float2bfloat16(x);   // RNE; compiler pairs into v_cvt_pk_bf16_f32
  u16 r; __builtin_memcpy(&r, &h, 2); return r;
}
__device__ __forceinline__ float bf2f(u16 v) {
  union { u32 u; float f; } c; c.u = ((u32)v) << 16; return c.f;
}

__global__ __launch_bounds__(256) void zero_kernel(float4* __restrict__ p, int n4) {
  int i = blockIdx.x * 256 + threadIdx.x;
  if (i < n4) p[i] = make_float4(0.f, 0.f, 0.f, 0.f);
}

// all 5 weight conversions in one launch
__global__ __launch_bounds__(256) void convert_all(
    const float* __restrict__ Wp0, const float* __restrict__ Wp1,
    const float* __restrict__ Wp2, const float* __restrict__ Wc0,
    const float* __restrict__ Wc1,
    u16* __restrict__ Wpb0, u16* __restrict__ Wpb1, u16* __restrict__ Wpb2,
    u16* __restrict__ Wcb0, u16* __restrict__ Wcb1)
{
  int i = blockIdx.x * 256 + threadIdx.x;
  const int P = F * CKP, Q = F * K2F;
  const float* W; u16* O; int K, KP, j;
  if      (i < P)         { W = Wp0; O = Wpb0; K = C;   KP = CKP; j = i; }
  else if (i < 2 * P)     { W = Wp1; O = Wpb1; K = C;   KP = CKP; j = i - P; }
  else if (i < 3 * P)     { W = Wp2; O = Wpb2; K = C;   KP = CKP; j = i - 2 * P; }
  else if (i < 3 * P + Q) { W = Wc0; O = Wcb0; K = K2F; KP = K2F; j = i - 3 * P; }
  else if (i < 3 * P + 2 * Q) { W = Wc1; O = Wcb1; K = K2F; KP = K2F; j = i - 3 * P - Q; }
  else return;
  int f = j / KP, k = j - f * KP;
  O[j] = (k < K) ? f2bf(W[(size_t)f * K + k]) : (u16)0;
}

// bucket-CSR build for both blocks in one launch (CAP slots per dst)
__global__ __launch_bounds__(256) void build_csr(
    const int* __restrict__ b0s, const int* __restrict__ b0d,
    const int* __restrict__ b1s, const int* __restrict__ b1d,
    int* __restrict__ deg0, int* __restrict__ deg1,
    int* __restrict__ csr0, int* __restrict__ csr1)
{
  int e = blockIdx.x * 256 + threadIdx.x;
  if (e < E0_) {
    int d = b0d[e];
    int slot = atomicAdd(&deg0[d], 1);
    if (slot < CAP) csr0[(size_t)d * CAP + slot] = b0s[e];
  } else {
    int e1 = e - E0_;
    if (e1 < E1_) {
      int d = b1d[e1];
      int slot = atomicAdd(&deg1[d], 1);
      if (slot < CAP) csr1[(size_t)d * CAP + slot] = b1s[e1];
    }
  }
}

// out[n][f] = bf16( emb[(nid[n]+1)*F+f] + lrelu(content[n,:] . Wp[f,:] + bp[f]) )
// MFMA bf16 16x16x32; block = 128 rows x 128 cols, 4 waves.
__global__ __launch_bounds__(256) void embed_mfma(
    const float* __restrict__ content, const u16* __restrict__ Wpb,
    const float* __restrict__ bp, const int* __restrict__ nid,
    const float* __restrict__ emb, u16* __restrict__ out, int ostride)
{
  __shared__ u16 As[128][LDA];
  __shared__ u16 Bs[128][LDA];
  const int t = threadIdx.x;
  const int lane = t & 63, w = t >> 6;
  const int row0 = blockIdx.x * 128;

  f32x4 acc[2][8];
#pragma unroll
  for (int fr = 0; fr < 2; ++fr)
#pragma unroll
    for (int fc = 0; fc < 8; ++fc) {
      acc[fr][fc][0] = 0.f; acc[fr][fc][1] = 0.f;
      acc[fr][fc][2] = 0.f; acc[fr][fc][3] = 0.f;
    }

  const int ar = t >> 1, ah = t & 1;
  const float* arow = content + (size_t)(row0 + ar) * C;

  for (int k0 = 0; k0 < CKP; k0 += 32) {
    if (k0) __syncthreads();
    // stage A: 16 fp32 -> bf16
    const float4* ap = (const float4*)(arow + k0 + ah * 16);
    float4 f0, f1, f2, f3;
    const float4 z4 = make_float4(0.f, 0.f, 0.f, 0.f);
    if (k0 == 288) {
      if (ah == 0) { f0 = ap[0]; f1 = ap[1]; f2 = ap[2]; f3 = z4; }
      else { f0 = z4; f1 = z4; f2 = z4; f3 = z4; }
    } else {
      f0 = ap[0]; f1 = ap[1]; f2 = ap[2]; f3 = ap[3];
    }
    u16x8 lo, hi;
    lo[0]=f2bf(f0.x); lo[1]=f2bf(f0.y); lo[2]=f2bf(f0.z); lo[3]=f2bf(f0.w);
    lo[4]=f2bf(f1.x); lo[5]=f2bf(f1.y); lo[6]=f2bf(f1.z); lo[7]=f2bf(f1.w);
    hi[0]=f2bf(f2.x); hi[1]=f2bf(f2.y); hi[2]=f2bf(f2.z); hi[3]=f2bf(f2.w);
    hi[4]=f2bf(f3.x); hi[5]=f2bf(f3.y); hi[6]=f2bf(f3.z); hi[7]=f2bf(f3.w);
    *(u16x8*)&As[ar][ah * 16]     = lo;
    *(u16x8*)&As[ar][ah * 16 + 8] = hi;
    // stage B: bf16 copy
#pragma unroll
    for (int it = 0; it < 2; ++it) {
      int cc = it * 256 + t;
      int j = cc >> 2, kc = (cc & 3) * 8;
      *(u16x8*)&Bs[j][kc] = *(const u16x8*)&Wpb[(size_t)j * CKP + k0 + kc];
    }
    __syncthreads();

    const int frow = lane & 15;
    const int kc = (lane >> 4) * 8;
    short8 a0 = *(const short8*)&As[w * 32 + frow][kc];
    short8 a1 = *(const short8*)&As[w * 32 + 16 + frow][kc];
#pragma unroll
    for (int fc = 0; fc < 8; ++fc) {
      short8 b = *(const short8*)&Bs[fc * 16 + frow][kc];
      acc[0][fc] = __builtin_amdgcn_mfma_f32_16x16x32_bf16(a0, b, acc[0][fc], 0, 0, 0);
      acc[1][fc] = __builtin_amdgcn_mfma_f32_16x16x32_bf16(a1, b, acc[1][fc], 0, 0, 0);
    }
  }

  float bpv[8];
#pragma unroll
  for (int fc = 0; fc < 8; ++fc) bpv[fc] = bp[fc * 16 + (lane & 15)];
#pragma unroll
  for (int fr = 0; fr < 2; ++fr) {
#pragma unroll
    for (int q = 0; q < 4; ++q) {
      int n = row0 + w * 32 + fr * 16 + (lane >> 4) * 4 + q;
      int g = nid[n] + 1;
      const float* erow = emb + (size_t)g * F;
      u16* orow = out + (size_t)n * ostride;
#pragma unroll
      for (int fc = 0; fc < 8; ++fc) {
        int col = fc * 16 + (lane & 15);
        float v = acc[fr][fc][q] + bpv[fc];
        orow[col] = f2bf(erow[col] + lrelu(v));
      }
    }
  }
}

// per dst d: xa = (sum_{src} hsrc[src] - h_self) / max(deg-1,1), bf16 into xcat[d][128:256]
// one wave per dst, 2 features per lane (u32 packed bf16 loads/stores)
__global__ __launch_bounds__(256) void gather_xa(
    const u16* __restrict__ hsrc, const int* __restrict__ csr,
    const int* __restrict__ deg, u16* __restrict__ xcat)
{
  int d = blockIdx.x * 4 + (threadIdx.x >> 6);
  int lane = threadIdx.x & 63;
  u32 hv = *(const u32*)&xcat[(size_t)d * (2 * F) + lane * 2];
  float h0f = bf2f((u16)(hv & 0xffff)), h1f = bf2f((u16)(hv >> 16));
  int dg = deg[d];
  int n = dg < CAP ? dg : CAP;
  const int* cp = csr + (size_t)d * CAP;
  float s0 = 0.f, s1 = 0.f;
  int j = 0;
  for (; j + 4 <= n; j += 4) {
    int i0 = cp[j], i1 = cp[j + 1], i2 = cp[j + 2], i3 = cp[j + 3];
    u32 v0 = *(const u32*)&hsrc[(size_t)i0 * F + lane * 2];
    u32 v1 = *(const u32*)&hsrc[(size_t)i1 * F + lane * 2];
    u32 v2 = *(const u32*)&hsrc[(size_t)i2 * F + lane * 2];
    u32 v3 = *(const u32*)&hsrc[(size_t)i3 * F + lane * 2];
    s0 += bf2f((u16)(v0 & 0xffff)) + bf2f((u16)(v1 & 0xffff))
        + bf2f((u16)(v2 & 0xffff)) + bf2f((u16)(v3 & 0xffff));
    s1 += bf2f((u16)(v0 >> 16)) + bf2f((u16)(v1 >> 16))
        + bf2f((u16)(v2 >> 16)) + bf2f((u16)(v3 >> 16));
  }
  for (; j < n; ++j) {
    u32 v = *(const u32*)&hsrc[(size_t)cp[j] * F + lane * 2];
    s0 += bf2f((u16)(v & 0xffff));
    s1 += bf2f((u16)(v >> 16));
  }
  float inv = 1.f / fmaxf((float)dg - 1.f, 1.f);
  u16 a0 = f2bf((s0 - h0f) * inv), a1 = f2bf((s1 - h1f) * inv);
  *(u32*)&xcat[(size_t)d * (2 * F) + F + lane * 2] = ((u32)a1 << 16) | a0;
}

// out[n] = normalize(lrelu(xcat[n,:] @ Wc.T + bc));  xcat bf16 [n][256]
template<int F32OUT>
__global__ __launch_bounds__(256) void conv_mfma(
    const u16* __restrict__ xcat, const u16* __restrict__ Wcb,
    const float* __restrict__ bc, u16* __restrict__ outb,
    float* __restrict__ outf)
{
  __shared__ u16 As[128][LDA];
  __shared__ u16 Bs[128][LDA];
  const int t = threadIdx.x;
  const int lane = t & 63, w = t >> 6;
  const int row0 = blockIdx.x * 128;

  f32x4 acc[2][8];
#pragma unroll
  for (int fr = 0; fr < 2; ++fr)
#pragma unroll
    for (int fc = 0; fc < 8; ++fc) {
      acc[fr][fc][0] = 0.f; acc[fr][fc][1] = 0.f;
      acc[fr][fc][2] = 0.f; acc[fr][fc][3] = 0.f;
    }

  for (int k0 = 0; k0 < K2F; k0 += 32) {
    if (k0) __syncthreads();
#pragma unroll
    for (int it = 0; it < 2; ++it) {
      int cc = it * 256 + t;
      int r = cc >> 2, kc = (cc & 3) * 8;
      *(u16x8*)&As[r][kc] = *(const u16x8*)&xcat[(size_t)(row0 + r) * K2F + k0 + kc];
      *(u16x8*)&Bs[r][kc] = *(const u16x8*)&Wcb[(size_t)r * K2F + k0 + kc];
    }
    __syncthreads();

    const int frow = lane & 15;
    const int kc = (lane >> 4) * 8;
    short8 a0 = *(const short8*)&As[w * 32 + frow][kc];
    short8 a1 = *(const short8*)&As[w * 32 + 16 + frow][kc];
#pragma unroll
    for (int fc = 0; fc < 8; ++fc) {
      short8 b = *(const short8*)&Bs[fc * 16 + frow][kc];
      acc[0][fc] = __builtin_amdgcn_mfma_f32_16x16x32_bf16(a0, b, acc[0][fc], 0, 0, 0);
      acc[1][fc] = __builtin_amdgcn_mfma_f32_16x16x32_bf16(a1, b, acc[1][fc], 0, 0, 0);
    }
  }

  float bcv[8];
#pragma unroll
  for (int fc = 0; fc < 8; ++fc) bcv[fc] = bc[fc * 16 + (lane & 15)];
#pragma unroll
  for (int fr = 0; fr < 2; ++fr) {
#pragma unroll
    for (int q = 0; q < 4; ++q) {
      float x[8];
      float ss = 0.f;
#pragma unroll
      for (int fc = 0; fc < 8; ++fc) {
        x[fc] = lrelu(acc[fr][fc][q] + bcv[fc]);
        ss += x[fc] * x[fc];
      }
#pragma unroll
      for (int m = 8; m >= 1; m >>= 1) ss += __shfl_xor(ss, m, 64);
      float nrm = 1.f / fmaxf(sqrtf(ss), 1e-6f);
      int n = row0 + w * 32 + fr * 16 + (lane >> 4) * 4 + q;
#pragma unroll
      for (int fc = 0; fc < 8; ++fc) {
        int col = fc * 16 + (lane & 15);
        if (F32OUT) outf[(size_t)n * F + col] = x[fc] * nrm;
        else        outb[(size_t)n * F + col] = f2bf(x[fc] * nrm);
      }
    }
  }
}

extern "C" void kernel_launch(void* const* d_in, const int* in_sizes, int n_in,
                              void* d_out, int out_size, void* d_ws, size_t ws_size,
                              hipStream_t stream) {
  const int*   nid0     = (const int*)d_in[0];
  const int*   nid1     = (const int*)d_in[1];
  const int*   nid2     = (const int*)d_in[2];
  const float* content0 = (const float*)d_in[3];
  const float* content1 = (const float*)d_in[4];
  const float* content2 = (const float*)d_in[5];
  const int*   b0s      = (const int*)d_in[6];
  const int*   b0d      = (const int*)d_in[7];
  const int*   b1s      = (const int*)d_in[8];
  const int*   b1d      = (const int*)d_in[9];
  const float* emb      = (const float*)d_in[10];
  const float* Wp0      = (const float*)d_in[11];
  const float* bp0      = (const float*)d_in[12];
  const float* Wp1      = (const float*)d_in[13];
  const float* bp1      = (const float*)d_in[14];
  const float* Wp2      = (const float*)d_in[15];
  const float* bp2      = (const float*)d_in[16];
  const float* Wc0      = (const float*)d_in[17];
  const float* bc0      = (const float*)d_in[18];
  const float* Wc1      = (const float*)d_in[19];
  const float* bc1      = (const float*)d_in[20];

  u16* wsu = (u16*)d_ws;
  u16* h0b   = wsu;                               // N0*F bf16
  u16* xcat1 = h0b + (size_t)N0_ * F;             // N1*256 bf16 (h1 | xa1)
  u16* xcat2 = xcat1 + (size_t)N1_ * 2 * F;       // N2*256 bf16 (h2 | xa2)
  u16* h1nb  = xcat2 + (size_t)N2_ * 2 * F;       // N1*F bf16 (conv0 out)
  u16* Wpb0  = h1nb + (size_t)N1_ * F;            // F*CKP bf16 each
  u16* Wpb1  = Wpb0 + (size_t)F * CKP;
  u16* Wpb2  = Wpb1 + (size_t)F * CKP;
  u16* Wcb0  = Wpb2 + (size_t)F * CKP;            // F*K2F bf16 each
  u16* Wcb1  = Wcb0 + (size_t)F * K2F;
  int* deg0  = (int*)(Wcb1 + (size_t)F * K2F);    // N1 } zeroed together
  int* deg1  = deg0 + N1_;                        // N2 }
  int* csr0  = deg1 + N2_;                        // N1*CAP
  int* csr1  = csr0 + (size_t)N1_ * CAP;          // N2*CAP

  // zero deg0|deg1 (contiguous, (N1+N2)*4 bytes, 16B-aligned)
  const int zn4 = (N1_ + N2_) / 4;
  zero_kernel<<<(zn4 + 255) / 256, 256, 0, stream>>>((float4*)deg0, zn4);

  build_csr<<<(E0_ + E1_ + 255) / 256, 256, 0, stream>>>(
      b0s, b0d, b1s, b1d, deg0, deg1, csr0, csr1);

  convert_all<<<(3 * F * CKP + 2 * F * K2F + 255) / 256, 256, 0, stream>>>(
      Wp0, Wp1, Wp2, Wc0, Wc1, Wpb0, Wpb1, Wpb2, Wcb0, Wcb1);

  embed_mfma<<<N0_ / 128, 256, 0, stream>>>(content0, Wpb0, bp0, nid0, emb, h0b, F);
  embed_mfma<<<N1_ / 128, 256, 0, stream>>>(content1, Wpb1, bp1, nid1, emb, xcat1, 2 * F);
  embed_mfma<<<N2_ / 128, 256, 0, stream>>>(content2, Wpb2, bp2, nid2, emb, xcat2, 2 * F);

  gather_xa<<<N1_ / 4, 256, 0, stream>>>(h0b, csr0, deg0, xcat1);
  conv_mfma<0><<<N1_ / 128, 256, 0, stream>>>(xcat1, Wcb0, bc0, h1nb, nullptr);

  gather_xa<<<N2_ / 4, 256, 0, stream>>>(h1nb, csr1, deg1, xcat2);
  conv_mfma<1><<<N2_ / 128, 256, 0, stream>>>(xcat2, Wcb1, bc1, nullptr, (float*)d_out);
}

// Round 6
// 332.050 us; speedup vs baseline: 3.7065x; 1.2666x over previous
//
#include <hip/hip_runtime.h>
#include <hip/hip_bf16.h>
#include <math.h>

#define F 128
#define C 300
#define CKP 320
#define K2F 256
#define N0_ 409600
#define N1_ 40960
#define N2_ 4096
#define E0_ 409600
#define E1_ 40960
#define CAP 64
#define LDA 40   // u16 row stride of conv LDS tiles

typedef unsigned short u16;
typedef unsigned int u32;
typedef __attribute__((ext_vector_type(8))) short short8;
typedef __attribute__((ext_vector_type(8))) unsigned short u16x8;
typedef __attribute__((ext_vector_type(4))) float f32x4;

__device__ __forceinline__ float lrelu(float x) { return x > 0.f ? x : 0.01f * x; }

__device__ __forceinline__ u16 f2bf(float x) {
  __hip_bfloat16 h = __float2bfloat16(x);   // RNE; pairs into v_cvt_pk_bf16_f32
  u16 r; __builtin_memcpy(&r, &h, 2); return r;
}
__device__ __forceinline__ float bf2f(u16 v) {
  union { u32 u; float f; } c; c.u = ((u32)v) << 16; return c.f;
}

#define GLOAD_LDS16(gp, lp) \
  __builtin_amdgcn_global_load_lds( \
      (const __attribute__((address_space(1))) void*)(const void*)(gp), \
      (__attribute__((address_space(3))) void*)(lp), 16, 0, 0)

__global__ __launch_bounds__(256) void zero_kernel(float4* __restrict__ p, int n4) {
  int i = blockIdx.x * 256 + threadIdx.x;
  if (i < n4) p[i] = make_float4(0.f, 0.f, 0.f, 0.f);
}

// all 5 weight conversions in one launch
__global__ __launch_bounds__(256) void convert_all(
    const float* __restrict__ Wp0, const float* __restrict__ Wp1,
    const float* __restrict__ Wp2, const float* __restrict__ Wc0,
    const float* __restrict__ Wc1,
    u16* __restrict__ Wpb0, u16* __restrict__ Wpb1, u16* __restrict__ Wpb2,
    u16* __restrict__ Wcb0, u16* __restrict__ Wcb1)
{
  int i = blockIdx.x * 256 + threadIdx.x;
  const int P = F * CKP, Q = F * K2F;
  const float* W; u16* O; int K, KP, j;
  if      (i < P)         { W = Wp0; O = Wpb0; K = C;   KP = CKP; j = i; }
  else if (i < 2 * P)     { W = Wp1; O = Wpb1; K = C;   KP = CKP; j = i - P; }
  else if (i < 3 * P)     { W = Wp2; O = Wpb2; K = C;   KP = CKP; j = i - 2 * P; }
  else if (i < 3 * P + Q) { W = Wc0; O = Wcb0; K = K2F; KP = K2F; j = i - 3 * P; }
  else if (i < 3 * P + 2 * Q) { W = Wc1; O = Wcb1; K = K2F; KP = K2F; j = i - 3 * P - Q; }
  else return;
  int f = j / KP, k = j - f * KP;
  O[j] = (k < K) ? f2bf(W[(size_t)f * K + k]) : (u16)0;
}

// bucket-CSR build for both blocks in one launch (CAP slots per dst)
__global__ __launch_bounds__(256) void build_csr(
    const int* __restrict__ b0s, const int* __restrict__ b0d,
    const int* __restrict__ b1s, const int* __restrict__ b1d,
    int* __restrict__ deg0, int* __restrict__ deg1,
    int* __restrict__ csr0, int* __restrict__ csr1)
{
  int e = blockIdx.x * 256 + threadIdx.x;
  if (e < E0_) {
    int d = b0d[e];
    int slot = atomicAdd(&deg0[d], 1);
    if (slot < CAP) csr0[(size_t)d * CAP + slot] = b0s[e];
  } else {
    int e1 = e - E0_;
    if (e1 < E1_) {
      int d = b1d[e1];
      int slot = atomicAdd(&deg1[d], 1);
      if (slot < CAP) csr1[(size_t)d * CAP + slot] = b1s[e1];
    }
  }
}

// out[n][f] = bf16( emb[(nid[n]+1)*F+f] + lrelu(content[n,:] . Wp[f,:] + bp[f]) )
// 2-phase pipelined: global_load_lds (w=16) into double-buffered LDS.
// A fp32 [128][32] linear, XOR-swizzled units (u ^= row&7); converted bf16 at frag read.
// B bf16 [128][32] linear, XOR-swizzled units (u ^= row&3).
__global__ __launch_bounds__(256) void embed_mfma(
    const float* __restrict__ content, const u16* __restrict__ Wpb,
    const float* __restrict__ bp, const int* __restrict__ nid,
    const float* __restrict__ emb, u16* __restrict__ out, int ostride,
    const float* __restrict__ zpad)
{
  __shared__ float As[2][128 * 32];   // 2 x 16 KB
  __shared__ u16  Bs[2][128 * 32];    // 2 x 8 KB
  const int t = threadIdx.x;
  const int lane = t & 63, w = t >> 6;
  const int row0 = blockIdx.x * 128;

  f32x4 acc[2][8];
#pragma unroll
  for (int fr = 0; fr < 2; ++fr)
#pragma unroll
    for (int fc = 0; fc < 8; ++fc) {
      acc[fr][fc][0] = 0.f; acc[fr][fc][1] = 0.f;
      acc[fr][fc][2] = 0.f; acc[fr][fc][3] = 0.f;
    }

  const int a_rl = lane >> 3, a_u = lane & 7;   // A staging: 8 rows x 8 units per instr
  const int b_rl = lane >> 2, b_u = lane & 3;   // B staging: 16 rows x 4 units per instr

  auto stage = [&](int buf, int k0) {
#pragma unroll
    for (int i = 0; i < 4; ++i) {               // A: 4 x 1024B per wave
      int r = w * 32 + i * 8 + a_rl;            // local row
      int v = a_u ^ (r & 7);                    // logical 16B unit (source pre-swizzle)
      const float* gp = (k0 == 288 && v >= 3)
          ? (zpad + v * 4)
          : (content + (size_t)(row0 + r) * C + k0 + v * 4);
      GLOAD_LDS16(gp, &As[buf][(w * 32 + i * 8) * 32]);
    }
#pragma unroll
    for (int j = 0; j < 2; ++j) {               // B: 2 x 1024B per wave
      int r = w * 32 + j * 16 + b_rl;
      int v = b_u ^ (r & 3);
      const u16* gp = Wpb + (size_t)r * CKP + k0 + v * 8;
      GLOAD_LDS16(gp, &Bs[buf][(w * 32 + j * 16) * 32]);
    }
  };

  stage(0, 0);
  __syncthreads();

  const int frow = lane & 15, g = lane >> 4;
  const int nt = CKP / 32;
  int cur = 0;
  for (int tstep = 0; tstep < nt; ++tstep) {
    if (tstep + 1 < nt) stage(cur ^ 1, (tstep + 1) * 32);

    // A fragments: rows w*32+frow (a0), +16 (a1); logical units 2g, 2g+1
    const int sw = frow & 7;
    const int u0 = (2 * g) ^ sw, u1 = (2 * g + 1) ^ sw;
    int ra0 = (w * 32 + frow) * 32, ra1 = (w * 32 + 16 + frow) * 32;
    float4 fa00 = *(const float4*)&As[cur][ra0 + u0 * 4];
    float4 fa01 = *(const float4*)&As[cur][ra0 + u1 * 4];
    float4 fa10 = *(const float4*)&As[cur][ra1 + u0 * 4];
    float4 fa11 = *(const float4*)&As[cur][ra1 + u1 * 4];
    u16x8 a0v, a1v;
    a0v[0]=f2bf(fa00.x); a0v[1]=f2bf(fa00.y); a0v[2]=f2bf(fa00.z); a0v[3]=f2bf(fa00.w);
    a0v[4]=f2bf(fa01.x); a0v[5]=f2bf(fa01.y); a0v[6]=f2bf(fa01.z); a0v[7]=f2bf(fa01.w);
    a1v[0]=f2bf(fa10.x); a1v[1]=f2bf(fa10.y); a1v[2]=f2bf(fa10.z); a1v[3]=f2bf(fa10.w);
    a1v[4]=f2bf(fa11.x); a1v[5]=f2bf(fa11.y); a1v[6]=f2bf(fa11.z); a1v[7]=f2bf(fa11.w);
    short8 a0 = *(short8*)&a0v, a1 = *(short8*)&a1v;

    const int bswz = frow & 3;
#pragma unroll
    for (int fc = 0; fc < 8; ++fc) {
      int rb = (fc * 16 + frow) * 32 + (g ^ bswz) * 8;
      short8 b = *(const short8*)&Bs[cur][rb];
      acc[0][fc] = __builtin_amdgcn_mfma_f32_16x16x32_bf16(a0, b, acc[0][fc], 0, 0, 0);
      acc[1][fc] = __builtin_amdgcn_mfma_f32_16x16x32_bf16(a1, b, acc[1][fc], 0, 0, 0);
    }
    __syncthreads();
    cur ^= 1;
  }

  float bpv[8];
#pragma unroll
  for (int fc = 0; fc < 8; ++fc) bpv[fc] = bp[fc * 16 + frow];
#pragma unroll
  for (int fr = 0; fr < 2; ++fr) {
#pragma unroll
    for (int q = 0; q < 4; ++q) {
      int n = row0 + w * 32 + fr * 16 + g * 4 + q;
      int gi = nid[n] + 1;
      const float* erow = emb + (size_t)gi * F;
      u16* orow = out + (size_t)n * ostride;
#pragma unroll
      for (int fc = 0; fc < 8; ++fc) {
        int col = fc * 16 + frow;
        float v = acc[fr][fc][q] + bpv[fc];
        orow[col] = f2bf(erow[col] + lrelu(v));
      }
    }
  }
}

// per dst d: xa = (sum_{src} hsrc[src] - h_self) / max(deg-1,1), bf16 into xcat[d][128:256]
__global__ __launch_bounds__(256) void gather_xa(
    const u16* __restrict__ hsrc, const int* __restrict__ csr,
    const int* __restrict__ deg, u16* __restrict__ xcat)
{
  int d = blockIdx.x * 4 + (threadIdx.x >> 6);
  int lane = threadIdx.x & 63;
  u32 hv = *(const u32*)&xcat[(size_t)d * (2 * F) + lane * 2];
  float h0f = bf2f((u16)(hv & 0xffff)), h1f = bf2f((u16)(hv >> 16));
  int dg = deg[d];
  int n = dg < CAP ? dg : CAP;
  const int* cp = csr + (size_t)d * CAP;
  float s0 = 0.f, s1 = 0.f;
  int j = 0;
  for (; j + 4 <= n; j += 4) {
    int i0 = cp[j], i1 = cp[j + 1], i2 = cp[j + 2], i3 = cp[j + 3];
    u32 v0 = *(const u32*)&hsrc[(size_t)i0 * F + lane * 2];
    u32 v1 = *(const u32*)&hsrc[(size_t)i1 * F + lane * 2];
    u32 v2 = *(const u32*)&hsrc[(size_t)i2 * F + lane * 2];
    u32 v3 = *(const u32*)&hsrc[(size_t)i3 * F + lane * 2];
    s0 += bf2f((u16)(v0 & 0xffff)) + bf2f((u16)(v1 & 0xffff))
        + bf2f((u16)(v2 & 0xffff)) + bf2f((u16)(v3 & 0xffff));
    s1 += bf2f((u16)(v0 >> 16)) + bf2f((u16)(v1 >> 16))
        + bf2f((u16)(v2 >> 16)) + bf2f((u16)(v3 >> 16));
  }
  for (; j < n; ++j) {
    u32 v = *(const u32*)&hsrc[(size_t)cp[j] * F + lane * 2];
    s0 += bf2f((u16)(v & 0xffff));
    s1 += bf2f((u16)(v >> 16));
  }
  float inv = 1.f / fmaxf((float)dg - 1.f, 1.f);
  u16 a0 = f2bf((s0 - h0f) * inv), a1 = f2bf((s1 - h1f) * inv);
  *(u32*)&xcat[(size_t)d * (2 * F) + F + lane * 2] = ((u32)a1 << 16) | a0;
}

// out[n] = normalize(lrelu(xcat[n,:] @ Wc.T + bc));  xcat bf16 [n][256]
template<int F32OUT>
__global__ __launch_bounds__(256) void conv_mfma(
    const u16* __restrict__ xcat, const u16* __restrict__ Wcb,
    const float* __restrict__ bc, u16* __restrict__ outb,
    float* __restrict__ outf)
{
  __shared__ u16 As[128][LDA];
  __shared__ u16 Bs[128][LDA];
  const int t = threadIdx.x;
  const int lane = t & 63, w = t >> 6;
  const int row0 = blockIdx.x * 128;

  f32x4 acc[2][8];
#pragma unroll
  for (int fr = 0; fr < 2; ++fr)
#pragma unroll
    for (int fc = 0; fc < 8; ++fc) {
      acc[fr][fc][0] = 0.f; acc[fr][fc][1] = 0.f;
      acc[fr][fc][2] = 0.f; acc[fr][fc][3] = 0.f;
    }

  for (int k0 = 0; k0 < K2F; k0 += 32) {
    if (k0) __syncthreads();
#pragma unroll
    for (int it = 0; it < 2; ++it) {
      int cc = it * 256 + t;
      int r = cc >> 2, kc = (cc & 3) * 8;
      *(u16x8*)&As[r][kc] = *(const u16x8*)&xcat[(size_t)(row0 + r) * K2F + k0 + kc];
      *(u16x8*)&Bs[r][kc] = *(const u16x8*)&Wcb[(size_t)r * K2F + k0 + kc];
    }
    __syncthreads();

    const int frow = lane & 15;
    const int kc = (lane >> 4) * 8;
    short8 a0 = *(const short8*)&As[w * 32 + frow][kc];
    short8 a1 = *(const short8*)&As[w * 32 + 16 + frow][kc];
#pragma unroll
    for (int fc = 0; fc < 8; ++fc) {
      short8 b = *(const short8*)&Bs[fc * 16 + frow][kc];
      acc[0][fc] = __builtin_amdgcn_mfma_f32_16x16x32_bf16(a0, b, acc[0][fc], 0, 0, 0);
      acc[1][fc] = __builtin_amdgcn_mfma_f32_16x16x32_bf16(a1, b, acc[1][fc], 0, 0, 0);
    }
  }

  float bcv[8];
#pragma unroll
  for (int fc = 0; fc < 8; ++fc) bcv[fc] = bc[fc * 16 + (lane & 15)];
#pragma unroll
  for (int fr = 0; fr < 2; ++fr) {
#pragma unroll
    for (int q = 0; q < 4; ++q) {
      float x[8];
      float ss = 0.f;
#pragma unroll
      for (int fc = 0; fc < 8; ++fc) {
        x[fc] = lrelu(acc[fr][fc][q] + bcv[fc]);
        ss += x[fc] * x[fc];
      }
#pragma unroll
      for (int m = 8; m >= 1; m >>= 1) ss += __shfl_xor(ss, m, 64);
      float nrm = 1.f / fmaxf(sqrtf(ss), 1e-6f);
      int n = row0 + w * 32 + fr * 16 + (lane >> 4) * 4 + q;
#pragma unroll
      for (int fc = 0; fc < 8; ++fc) {
        int col = fc * 16 + (lane & 15);
        if (F32OUT) outf[(size_t)n * F + col] = x[fc] * nrm;
        else        outb[(size_t)n * F + col] = f2bf(x[fc] * nrm);
      }
    }
  }
}

extern "C" void kernel_launch(void* const* d_in, const int* in_sizes, int n_in,
                              void* d_out, int out_size, void* d_ws, size_t ws_size,
                              hipStream_t stream) {
  const int*   nid0     = (const int*)d_in[0];
  const int*   nid1     = (const int*)d_in[1];
  const int*   nid2     = (const int*)d_in[2];
  const float* content0 = (const float*)d_in[3];
  const float* content1 = (const float*)d_in[4];
  const float* content2 = (const float*)d_in[5];
  const int*   b0s      = (const int*)d_in[6];
  const int*   b0d      = (const int*)d_in[7];
  const int*   b1s      = (const int*)d_in[8];
  const int*   b1d      = (const int*)d_in[9];
  const float* emb      = (const float*)d_in[10];
  const float* Wp0      = (const float*)d_in[11];
  const float* bp0      = (const float*)d_in[12];
  const float* Wp1      = (const float*)d_in[13];
  const float* bp1      = (const float*)d_in[14];
  const float* Wp2      = (const float*)d_in[15];
  const float* bp2      = (const float*)d_in[16];
  const float* Wc0      = (const float*)d_in[17];
  const float* bc0      = (const float*)d_in[18];
  const float* Wc1      = (const float*)d_in[19];
  const float* bc1      = (const float*)d_in[20];

  u16* wsu = (u16*)d_ws;
  u16* h0b   = wsu;                               // N0*F bf16
  u16* xcat1 = h0b + (size_t)N0_ * F;             // N1*256 bf16 (h1 | xa1)
  u16* xcat2 = xcat1 + (size_t)N1_ * 2 * F;       // N2*256 bf16 (h2 | xa2)
  u16* h1nb  = xcat2 + (size_t)N2_ * 2 * F;       // N1*F bf16 (conv0 out)
  u16* Wpb0  = h1nb + (size_t)N1_ * F;            // F*CKP bf16 each
  u16* Wpb1  = Wpb0 + (size_t)F * CKP;
  u16* Wpb2  = Wpb1 + (size_t)F * CKP;
  u16* Wcb0  = Wpb2 + (size_t)F * CKP;            // F*K2F bf16 each
  u16* Wcb1  = Wcb0 + (size_t)F * K2F;
  float* zpad = (float*)(Wcb1 + (size_t)F * K2F); // 64 floats } zeroed together
  int* deg0  = (int*)(zpad + 64);                 // N1         }
  int* deg1  = deg0 + N1_;                        // N2         }
  int* csr0  = deg1 + N2_;                        // N1*CAP
  int* csr1  = csr0 + (size_t)N1_ * CAP;          // N2*CAP

  // zero zpad|deg0|deg1 (contiguous, 16B-aligned)
  const int zn4 = (64 + N1_ + N2_) / 4;
  zero_kernel<<<(zn4 + 255) / 256, 256, 0, stream>>>((float4*)zpad, zn4);

  build_csr<<<(E0_ + E1_ + 255) / 256, 256, 0, stream>>>(
      b0s, b0d, b1s, b1d, deg0, deg1, csr0, csr1);

  convert_all<<<(3 * F * CKP + 2 * F * K2F + 255) / 256, 256, 0, stream>>>(
      Wp0, Wp1, Wp2, Wc0, Wc1, Wpb0, Wpb1, Wpb2, Wcb0, Wcb1);

  embed_mfma<<<N0_ / 128, 256, 0, stream>>>(content0, Wpb0, bp0, nid0, emb, h0b, F, zpad);
  embed_mfma<<<N1_ / 128, 256, 0, stream>>>(content1, Wpb1, bp1, nid1, emb, xcat1, 2 * F, zpad);
  embed_mfma<<<N2_ / 128, 256, 0, stream>>>(content2, Wpb2, bp2, nid2, emb, xcat2, 2 * F, zpad);

  gather_xa<<<N1_ / 4, 256, 0, stream>>>(h0b, csr0, deg0, xcat1);
  conv_mfma<0><<<N1_ / 128, 256, 0, stream>>>(xcat1, Wcb0, bc0, h1nb, nullptr);

  gather_xa<<<N2_ / 4, 256, 0, stream>>>(h1nb, csr1, deg1, xcat2);
  conv_mfma<1><<<N2_ / 128, 256, 0, stream>>>(xcat2, Wcb1, bc1, nullptr, (float*)d_out);
}

// Round 7
// 321.590 us; speedup vs baseline: 3.8270x; 1.0325x over previous
//
#include <hip/hip_runtime.h>
#include <hip/hip_bf16.h>
#include <math.h>

#define F 128
#define C 300
#define CKP 320
#define NKT 10        // CKP/32 k-steps
#define K2F 256
#define N0_ 409600
#define N1_ 40960
#define N2_ 4096
#define E0_ 409600
#define E1_ 40960
#define CAP 64
#define LDA 40        // u16 row stride of conv LDS tiles

typedef unsigned short u16;
typedef unsigned int u32;
typedef __attribute__((ext_vector_type(8))) short short8;
typedef __attribute__((ext_vector_type(8))) unsigned short u16x8;
typedef __attribute__((ext_vector_type(4))) float f32x4;

__device__ __forceinline__ float lrelu(float x) { return x > 0.f ? x : 0.01f * x; }

__device__ __forceinline__ u16 f2bf(float x) {
  __hip_bfloat16 h = __float2bfloat16(x);   // RNE; pairs into v_cvt_pk_bf16_f32
  u16 r; __builtin_memcpy(&r, &h, 2); return r;
}
__device__ __forceinline__ float bf2f(u16 v) {
  union { u32 u; float f; } c; c.u = ((u32)v) << 16; return c.f;
}

#define GLOAD_LDS16(gp, lp) \
  __builtin_amdgcn_global_load_lds( \
      (const __attribute__((address_space(1))) void*)(const void*)(gp), \
      (__attribute__((address_space(3))) void*)(lp), 16, 0, 0)

__global__ __launch_bounds__(256) void zero_kernel(float4* __restrict__ p, int n4) {
  int i = blockIdx.x * 256 + threadIdx.x;
  if (i < n4) p[i] = make_float4(0.f, 0.f, 0.f, 0.f);
}

// all 5 weight conversions in one launch
__global__ __launch_bounds__(256) void convert_all(
    const float* __restrict__ Wp0, const float* __restrict__ Wp1,
    const float* __restrict__ Wp2, const float* __restrict__ Wc0,
    const float* __restrict__ Wc1,
    u16* __restrict__ Wpb0, u16* __restrict__ Wpb1, u16* __restrict__ Wpb2,
    u16* __restrict__ Wcb0, u16* __restrict__ Wcb1)
{
  int i = blockIdx.x * 256 + threadIdx.x;
  const int P = F * CKP, Q = F * K2F;
  const float* W; u16* O; int K, KP, j;
  if      (i < P)         { W = Wp0; O = Wpb0; K = C;   KP = CKP; j = i; }
  else if (i < 2 * P)     { W = Wp1; O = Wpb1; K = C;   KP = CKP; j = i - P; }
  else if (i < 3 * P)     { W = Wp2; O = Wpb2; K = C;   KP = CKP; j = i - 2 * P; }
  else if (i < 3 * P + Q) { W = Wc0; O = Wcb0; K = K2F; KP = K2F; j = i - 3 * P; }
  else if (i < 3 * P + 2 * Q) { W = Wc1; O = Wcb1; K = K2F; KP = K2F; j = i - 3 * P - Q; }
  else return;
  int f = j / KP, k = j - f * KP;
  O[j] = (k < K) ? f2bf(W[(size_t)f * K + k]) : (u16)0;
}

// bucket-CSR build for both blocks in one launch (CAP slots per dst)
__global__ __launch_bounds__(256) void build_csr(
    const int* __restrict__ b0s, const int* __restrict__ b0d,
    const int* __restrict__ b1s, const int* __restrict__ b1d,
    int* __restrict__ deg0, int* __restrict__ deg1,
    int* __restrict__ csr0, int* __restrict__ csr1)
{
  int e = blockIdx.x * 256 + threadIdx.x;
  if (e < E0_) {
    int d = b0d[e];
    int slot = atomicAdd(&deg0[d], 1);
    if (slot < CAP) csr0[(size_t)d * CAP + slot] = b0s[e];
  } else {
    int e1 = e - E0_;
    if (e1 < E1_) {
      int d = b1d[e1];
      int slot = atomicAdd(&deg1[d], 1);
      if (slot < CAP) csr1[(size_t)d * CAP + slot] = b1s[e1];
    }
  }
}

struct Afrag { float4 x00, x01, x10, x11; };

// Fused embed for all 3 layers. B resident in LDS (80KB, staged once),
// A global->register with depth-2 static prefetch, NO in-loop barriers.
__global__ __launch_bounds__(256, 2) void embed_all(
    const float* __restrict__ content0, const float* __restrict__ content1,
    const float* __restrict__ content2,
    const u16* __restrict__ Wpb0, const u16* __restrict__ Wpb1,
    const u16* __restrict__ Wpb2,
    const float* __restrict__ bp0, const float* __restrict__ bp1,
    const float* __restrict__ bp2,
    const int* __restrict__ nid0, const int* __restrict__ nid1,
    const int* __restrict__ nid2,
    const float* __restrict__ emb,
    u16* __restrict__ out0, u16* __restrict__ out1, u16* __restrict__ out2)
{
  __shared__ u16 Bs[NKT * 128 * 32];   // 80 KB: [kt][j][32], 16B units XOR-swizzled by j&3
  const int t = threadIdx.x, lane = t & 63, w = t >> 6;
  const int b = blockIdx.x;

  const float* content; const u16* Wpb; const float* bp; const int* nid;
  u16* out; int ostride, row0;
  if (b < N0_ / 128) {
    content = content0; Wpb = Wpb0; bp = bp0; nid = nid0;
    out = out0; ostride = F; row0 = b * 128;
  } else if (b < N0_ / 128 + N1_ / 128) {
    content = content1; Wpb = Wpb1; bp = bp1; nid = nid1;
    out = out1; ostride = 2 * F; row0 = (b - N0_ / 128) * 128;
  } else {
    content = content2; Wpb = Wpb2; bp = bp2; nid = nid2;
    out = out2; ostride = 2 * F; row0 = (b - N0_ / 128 - N1_ / 128) * 128;
  }

  // ---- stage whole B once (each wave: 20 x 1KB chunks) ----
  {
    const int j_in = lane >> 2, u_in = lane & 3;
#pragma unroll
    for (int cc = 0; cc < 20; ++cc) {
      int c = w * 20 + cc;
      int kt = c >> 3, j0 = (c & 7) * 16;
      int j = j0 + j_in;
      int u = u_in ^ (j & 3);                 // pre-swizzled global source
      const u16* gp = Wpb + (size_t)j * CKP + kt * 32 + u * 8;
      GLOAD_LDS16(gp, &Bs[(size_t)(kt * 128 + j0) * 32]);
    }
  }

  f32x4 acc[2][8];
#pragma unroll
  for (int fr = 0; fr < 2; ++fr)
#pragma unroll
    for (int fc = 0; fc < 8; ++fc) {
      acc[fr][fc][0] = 0.f; acc[fr][fc][1] = 0.f;
      acc[fr][fc][2] = 0.f; acc[fr][fc][3] = 0.f;
    }

  const int frow = lane & 15, g = lane >> 4;
  const float* c0p = content + (size_t)(row0 + w * 32 + frow) * C;
  const float* c1p = c0p + (size_t)16 * C;

  auto loadA = [&](int kt) -> Afrag {
    Afrag r;
    int col = kt * 32 + g * 8;
    if (kt < NKT - 1) {
      r.x00 = *(const float4*)(c0p + col); r.x01 = *(const float4*)(c0p + col + 4);
      r.x10 = *(const float4*)(c1p + col); r.x11 = *(const float4*)(c1p + col + 4);
    } else {                                // K tail: cols 288..319, valid < 300
      float v0[8], v1[8];
#pragma unroll
      for (int i = 0; i < 8; ++i) {
        int cc = col + i;
        v0[i] = (cc < C) ? c0p[cc] : 0.f;
        v1[i] = (cc < C) ? c1p[cc] : 0.f;
      }
      r.x00 = make_float4(v0[0], v0[1], v0[2], v0[3]);
      r.x01 = make_float4(v0[4], v0[5], v0[6], v0[7]);
      r.x10 = make_float4(v1[0], v1[1], v1[2], v1[3]);
      r.x11 = make_float4(v1[4], v1[5], v1[6], v1[7]);
    }
    return r;
  };

  const int bsw = (g ^ (frow & 3)) * 8;
  auto compute = [&](const Afrag& a, int kt) {
    u16x8 a0v, a1v;
    a0v[0]=f2bf(a.x00.x); a0v[1]=f2bf(a.x00.y); a0v[2]=f2bf(a.x00.z); a0v[3]=f2bf(a.x00.w);
    a0v[4]=f2bf(a.x01.x); a0v[5]=f2bf(a.x01.y); a0v[6]=f2bf(a.x01.z); a0v[7]=f2bf(a.x01.w);
    a1v[0]=f2bf(a.x10.x); a1v[1]=f2bf(a.x10.y); a1v[2]=f2bf(a.x10.z); a1v[3]=f2bf(a.x10.w);
    a1v[4]=f2bf(a.x11.x); a1v[5]=f2bf(a.x11.y); a1v[6]=f2bf(a.x11.z); a1v[7]=f2bf(a.x11.w);
    short8 a0 = *(short8*)&a0v, a1 = *(short8*)&a1v;
#pragma unroll
    for (int fc = 0; fc < 8; ++fc) {
      short8 bfr = *(const short8*)&Bs[(size_t)(kt * 128 + fc * 16 + frow) * 32 + bsw];
      acc[0][fc] = __builtin_amdgcn_mfma_f32_16x16x32_bf16(a0, bfr, acc[0][fc], 0, 0, 0);
      acc[1][fc] = __builtin_amdgcn_mfma_f32_16x16x32_bf16(a1, bfr, acc[1][fc], 0, 0, 0);
    }
  };

  // depth-2 static register pipeline, zero in-loop barriers
  Afrag A0 = loadA(0);
  Afrag A1 = loadA(1);
  __syncthreads();                 // B resident from here on
  Afrag A2 = loadA(2); compute(A0, 0);
  Afrag A3 = loadA(3); compute(A1, 1);
  A0 = loadA(4);       compute(A2, 2);
  A1 = loadA(5);       compute(A3, 3);
  A2 = loadA(6);       compute(A0, 4);
  A3 = loadA(7);       compute(A1, 5);
  A0 = loadA(8);       compute(A2, 6);
  A1 = loadA(9);       compute(A3, 7);
  compute(A0, 8);
  compute(A1, 9);

  // ---- epilogue: bias + lrelu + emb gather, bf16 store ----
  float bpv[8];
#pragma unroll
  for (int fc = 0; fc < 8; ++fc) bpv[fc] = bp[fc * 16 + frow];
#pragma unroll
  for (int fr = 0; fr < 2; ++fr) {
#pragma unroll
    for (int q = 0; q < 4; ++q) {
      int n = row0 + w * 32 + fr * 16 + g * 4 + q;
      int gi = nid[n] + 1;
      const float* erow = emb + (size_t)gi * F;
      u16* orow = out + (size_t)n * ostride;
#pragma unroll
      for (int fc = 0; fc < 8; ++fc) {
        int col = fc * 16 + frow;
        float v = acc[fr][fc][q] + bpv[fc];
        orow[col] = f2bf(erow[col] + lrelu(v));
      }
    }
  }
}

// per dst d: xa = (sum_{src} hsrc[src] - h_self) / max(deg-1,1), bf16 into xcat[d][128:256]
__global__ __launch_bounds__(256) void gather_xa(
    const u16* __restrict__ hsrc, const int* __restrict__ csr,
    const int* __restrict__ deg, u16* __restrict__ xcat)
{
  int d = blockIdx.x * 4 + (threadIdx.x >> 6);
  int lane = threadIdx.x & 63;
  u32 hv = *(const u32*)&xcat[(size_t)d * (2 * F) + lane * 2];
  float h0f = bf2f((u16)(hv & 0xffff)), h1f = bf2f((u16)(hv >> 16));
  int dg = deg[d];
  int n = dg < CAP ? dg : CAP;
  const int* cp = csr + (size_t)d * CAP;
  float s0 = 0.f, s1 = 0.f;
  int j = 0;
  for (; j + 4 <= n; j += 4) {
    int i0 = cp[j], i1 = cp[j + 1], i2 = cp[j + 2], i3 = cp[j + 3];
    u32 v0 = *(const u32*)&hsrc[(size_t)i0 * F + lane * 2];
    u32 v1 = *(const u32*)&hsrc[(size_t)i1 * F + lane * 2];
    u32 v2 = *(const u32*)&hsrc[(size_t)i2 * F + lane * 2];
    u32 v3 = *(const u32*)&hsrc[(size_t)i3 * F + lane * 2];
    s0 += bf2f((u16)(v0 & 0xffff)) + bf2f((u16)(v1 & 0xffff))
        + bf2f((u16)(v2 & 0xffff)) + bf2f((u16)(v3 & 0xffff));
    s1 += bf2f((u16)(v0 >> 16)) + bf2f((u16)(v1 >> 16))
        + bf2f((u16)(v2 >> 16)) + bf2f((u16)(v3 >> 16));
  }
  for (; j < n; ++j) {
    u32 v = *(const u32*)&hsrc[(size_t)cp[j] * F + lane * 2];
    s0 += bf2f((u16)(v & 0xffff));
    s1 += bf2f((u16)(v >> 16));
  }
  float inv = 1.f / fmaxf((float)dg - 1.f, 1.f);
  u16 a0 = f2bf((s0 - h0f) * inv), a1 = f2bf((s1 - h1f) * inv);
  *(u32*)&xcat[(size_t)d * (2 * F) + F + lane * 2] = ((u32)a1 << 16) | a0;
}

// out[n] = normalize(lrelu(xcat[n,:] @ Wc.T + bc));  xcat bf16 [n][256]
template<int F32OUT>
__global__ __launch_bounds__(256) void conv_mfma(
    const u16* __restrict__ xcat, const u16* __restrict__ Wcb,
    const float* __restrict__ bc, u16* __restrict__ outb,
    float* __restrict__ outf)
{
  __shared__ u16 As[128][LDA];
  __shared__ u16 Bs[128][LDA];
  const int t = threadIdx.x;
  const int lane = t & 63, w = t >> 6;
  const int row0 = blockIdx.x * 128;

  f32x4 acc[2][8];
#pragma unroll
  for (int fr = 0; fr < 2; ++fr)
#pragma unroll
    for (int fc = 0; fc < 8; ++fc) {
      acc[fr][fc][0] = 0.f; acc[fr][fc][1] = 0.f;
      acc[fr][fc][2] = 0.f; acc[fr][fc][3] = 0.f;
    }

  for (int k0 = 0; k0 < K2F; k0 += 32) {
    if (k0) __syncthreads();
#pragma unroll
    for (int it = 0; it < 2; ++it) {
      int cc = it * 256 + t;
      int r = cc >> 2, kc = (cc & 3) * 8;
      *(u16x8*)&As[r][kc] = *(const u16x8*)&xcat[(size_t)(row0 + r) * K2F + k0 + kc];
      *(u16x8*)&Bs[r][kc] = *(const u16x8*)&Wcb[(size_t)r * K2F + k0 + kc];
    }
    __syncthreads();

    const int frow = lane & 15;
    const int kc = (lane >> 4) * 8;
    short8 a0 = *(const short8*)&As[w * 32 + frow][kc];
    short8 a1 = *(const short8*)&As[w * 32 + 16 + frow][kc];
#pragma unroll
    for (int fc = 0; fc < 8; ++fc) {
      short8 b = *(const short8*)&Bs[fc * 16 + frow][kc];
      acc[0][fc] = __builtin_amdgcn_mfma_f32_16x16x32_bf16(a0, b, acc[0][fc], 0, 0, 0);
      acc[1][fc] = __builtin_amdgcn_mfma_f32_16x16x32_bf16(a1, b, acc[1][fc], 0, 0, 0);
    }
  }

  float bcv[8];
#pragma unroll
  for (int fc = 0; fc < 8; ++fc) bcv[fc] = bc[fc * 16 + (lane & 15)];
#pragma unroll
  for (int fr = 0; fr < 2; ++fr) {
#pragma unroll
    for (int q = 0; q < 4; ++q) {
      float x[8];
      float ss = 0.f;
#pragma unroll
      for (int fc = 0; fc < 8; ++fc) {
        x[fc] = lrelu(acc[fr][fc][q] + bcv[fc]);
        ss += x[fc] * x[fc];
      }
#pragma unroll
      for (int m = 8; m >= 1; m >>= 1) ss += __shfl_xor(ss, m, 64);
      float nrm = 1.f / fmaxf(sqrtf(ss), 1e-6f);
      int n = row0 + w * 32 + fr * 16 + (lane >> 4) * 4 + q;
#pragma unroll
      for (int fc = 0; fc < 8; ++fc) {
        int col = fc * 16 + (lane & 15);
        if (F32OUT) outf[(size_t)n * F + col] = x[fc] * nrm;
        else        outb[(size_t)n * F + col] = f2bf(x[fc] * nrm);
      }
    }
  }
}

extern "C" void kernel_launch(void* const* d_in, const int* in_sizes, int n_in,
                              void* d_out, int out_size, void* d_ws, size_t ws_size,
                              hipStream_t stream) {
  const int*   nid0     = (const int*)d_in[0];
  const int*   nid1     = (const int*)d_in[1];
  const int*   nid2     = (const int*)d_in[2];
  const float* content0 = (const float*)d_in[3];
  const float* content1 = (const float*)d_in[4];
  const float* content2 = (const float*)d_in[5];
  const int*   b0s      = (const int*)d_in[6];
  const int*   b0d      = (const int*)d_in[7];
  const int*   b1s      = (const int*)d_in[8];
  const int*   b1d      = (const int*)d_in[9];
  const float* emb      = (const float*)d_in[10];
  const float* Wp0      = (const float*)d_in[11];
  const float* bp0      = (const float*)d_in[12];
  const float* Wp1      = (const float*)d_in[13];
  const float* bp1      = (const float*)d_in[14];
  const float* Wp2      = (const float*)d_in[15];
  const float* bp2      = (const float*)d_in[16];
  const float* Wc0      = (const float*)d_in[17];
  const float* bc0      = (const float*)d_in[18];
  const float* Wc1      = (const float*)d_in[19];
  const float* bc1      = (const float*)d_in[20];

  u16* wsu = (u16*)d_ws;
  u16* h0b   = wsu;                               // N0*F bf16
  u16* xcat1 = h0b + (size_t)N0_ * F;             // N1*256 bf16 (h1 | xa1)
  u16* xcat2 = xcat1 + (size_t)N1_ * 2 * F;       // N2*256 bf16 (h2 | xa2)
  u16* h1nb  = xcat2 + (size_t)N2_ * 2 * F;       // N1*F bf16 (conv0 out)
  u16* Wpb0  = h1nb + (size_t)N1_ * F;            // F*CKP bf16 each
  u16* Wpb1  = Wpb0 + (size_t)F * CKP;
  u16* Wpb2  = Wpb1 + (size_t)F * CKP;
  u16* Wcb0  = Wpb2 + (size_t)F * CKP;            // F*K2F bf16 each
  u16* Wcb1  = Wcb0 + (size_t)F * K2F;
  int* deg0  = (int*)(Wcb1 + (size_t)F * K2F);    // N1 } zeroed together
  int* deg1  = deg0 + N1_;                        // N2 }
  int* csr0  = deg1 + N2_;                        // N1*CAP
  int* csr1  = csr0 + (size_t)N1_ * CAP;          // N2*CAP

  // zero deg0|deg1 (contiguous, 16B-aligned)
  const int zn4 = (N1_ + N2_) / 4;
  zero_kernel<<<(zn4 + 255) / 256, 256, 0, stream>>>((float4*)deg0, zn4);

  build_csr<<<(E0_ + E1_ + 255) / 256, 256, 0, stream>>>(
      b0s, b0d, b1s, b1d, deg0, deg1, csr0, csr1);

  convert_all<<<(3 * F * CKP + 2 * F * K2F + 255) / 256, 256, 0, stream>>>(
      Wp0, Wp1, Wp2, Wc0, Wc1, Wpb0, Wpb1, Wpb2, Wcb0, Wcb1);

  embed_all<<<(N0_ + N1_ + N2_) / 128, 256, 0, stream>>>(
      content0, content1, content2, Wpb0, Wpb1, Wpb2,
      bp0, bp1, bp2, nid0, nid1, nid2, emb, h0b, xcat1, xcat2);

  gather_xa<<<N1_ / 4, 256, 0, stream>>>(h0b, csr0, deg0, xcat1);
  conv_mfma<0><<<N1_ / 128, 256, 0, stream>>>(xcat1, Wcb0, bc0, h1nb, nullptr);

  gather_xa<<<N2_ / 4, 256, 0, stream>>>(h1nb, csr1, deg1, xcat2);
  conv_mfma<1><<<N2_ / 128, 256, 0, stream>>>(xcat2, Wcb1, bc1, nullptr, (float*)d_out);
}

// Round 8
// 318.133 us; speedup vs baseline: 3.8686x; 1.0109x over previous
//
#include <hip/hip_runtime.h>
#include <hip/hip_bf16.h>
#include <math.h>

#define F 128
#define C 300
#define CKP 320
#define NKT 10        // CKP/32 k-steps
#define K2F 256
#define N0_ 409600
#define N1_ 40960
#define N2_ 4096
#define E0_ 409600
#define E1_ 40960
#define CAP 64
#define LDA 40        // u16 row stride of conv LDS tiles

typedef unsigned short u16;
typedef unsigned int u32;
typedef __attribute__((ext_vector_type(8))) short short8;
typedef __attribute__((ext_vector_type(8))) unsigned short u16x8;
typedef __attribute__((ext_vector_type(4))) float f32x4;

__device__ __forceinline__ float lrelu(float x) { return x > 0.f ? x : 0.01f * x; }

__device__ __forceinline__ u16 f2bf(float x) {
  __hip_bfloat16 h = __float2bfloat16(x);   // RNE; pairs into v_cvt_pk_bf16_f32
  u16 r; __builtin_memcpy(&r, &h, 2); return r;
}
__device__ __forceinline__ float bf2f(u16 v) {
  union { u32 u; float f; } c; c.u = ((u32)v) << 16; return c.f;
}

#define GLOAD_LDS16(gp, lp) \
  __builtin_amdgcn_global_load_lds( \
      (const __attribute__((address_space(1))) void*)(const void*)(gp), \
      (__attribute__((address_space(3))) void*)(lp), 16, 0, 0)

__global__ __launch_bounds__(256) void zero_kernel(float4* __restrict__ p, int n4) {
  int i = blockIdx.x * 256 + threadIdx.x;
  if (i < n4) p[i] = make_float4(0.f, 0.f, 0.f, 0.f);
}

// all 5 weight conversions in one launch
__global__ __launch_bounds__(256) void convert_all(
    const float* __restrict__ Wp0, const float* __restrict__ Wp1,
    const float* __restrict__ Wp2, const float* __restrict__ Wc0,
    const float* __restrict__ Wc1,
    u16* __restrict__ Wpb0, u16* __restrict__ Wpb1, u16* __restrict__ Wpb2,
    u16* __restrict__ Wcb0, u16* __restrict__ Wcb1)
{
  int i = blockIdx.x * 256 + threadIdx.x;
  const int P = F * CKP, Q = F * K2F;
  const float* W; u16* O; int K, KP, j;
  if      (i < P)         { W = Wp0; O = Wpb0; K = C;   KP = CKP; j = i; }
  else if (i < 2 * P)     { W = Wp1; O = Wpb1; K = C;   KP = CKP; j = i - P; }
  else if (i < 3 * P)     { W = Wp2; O = Wpb2; K = C;   KP = CKP; j = i - 2 * P; }
  else if (i < 3 * P + Q) { W = Wc0; O = Wcb0; K = K2F; KP = K2F; j = i - 3 * P; }
  else if (i < 3 * P + 2 * Q) { W = Wc1; O = Wcb1; K = K2F; KP = K2F; j = i - 3 * P - Q; }
  else return;
  int f = j / KP, k = j - f * KP;
  O[j] = (k < K) ? f2bf(W[(size_t)f * K + k]) : (u16)0;
}

// bucket-CSR build for both blocks in one launch (CAP slots per dst)
__global__ __launch_bounds__(256) void build_csr(
    const int* __restrict__ b0s, const int* __restrict__ b0d,
    const int* __restrict__ b1s, const int* __restrict__ b1d,
    int* __restrict__ deg0, int* __restrict__ deg1,
    int* __restrict__ csr0, int* __restrict__ csr1)
{
  int e = blockIdx.x * 256 + threadIdx.x;
  if (e < E0_) {
    int d = b0d[e];
    int slot = atomicAdd(&deg0[d], 1);
    if (slot < CAP) csr0[(size_t)d * CAP + slot] = b0s[e];
  } else {
    int e1 = e - E0_;
    if (e1 < E1_) {
      int d = b1d[e1];
      int slot = atomicAdd(&deg1[d], 1);
      if (slot < CAP) csr1[(size_t)d * CAP + slot] = b1s[e1];
    }
  }
}

struct Afrag { float4 x00, x01, x10, x11; };

// Fused embed for all 3 layers. B resident in LDS (80KB, staged once),
// A global->register with depth-3 static prefetch, NO in-loop barriers.
__global__ __launch_bounds__(256, 2) void embed_all(
    const float* __restrict__ content0, const float* __restrict__ content1,
    const float* __restrict__ content2,
    const u16* __restrict__ Wpb0, const u16* __restrict__ Wpb1,
    const u16* __restrict__ Wpb2,
    const float* __restrict__ bp0, const float* __restrict__ bp1,
    const float* __restrict__ bp2,
    const int* __restrict__ nid0, const int* __restrict__ nid1,
    const int* __restrict__ nid2,
    const float* __restrict__ emb,
    u16* __restrict__ out0, u16* __restrict__ out1, u16* __restrict__ out2)
{
  __shared__ u16 Bs[NKT * 128 * 32];   // 80 KB: [kt][j][32], 16B units XOR-swizzled by j&3
  const int t = threadIdx.x, lane = t & 63, w = t >> 6;
  const int b = blockIdx.x;

  const float* content; const u16* Wpb; const float* bp; const int* nid;
  u16* out; int ostride, row0;
  if (b < N0_ / 128) {
    content = content0; Wpb = Wpb0; bp = bp0; nid = nid0;
    out = out0; ostride = F; row0 = b * 128;
  } else if (b < N0_ / 128 + N1_ / 128) {
    content = content1; Wpb = Wpb1; bp = bp1; nid = nid1;
    out = out1; ostride = 2 * F; row0 = (b - N0_ / 128) * 128;
  } else {
    content = content2; Wpb = Wpb2; bp = bp2; nid = nid2;
    out = out2; ostride = 2 * F; row0 = (b - N0_ / 128 - N1_ / 128) * 128;
  }

  // ---- stage whole B once (each wave: 20 x 1KB chunks) ----
  {
    const int j_in = lane >> 2, u_in = lane & 3;
#pragma unroll
    for (int cc = 0; cc < 20; ++cc) {
      int c = w * 20 + cc;
      int kt = c >> 3, j0 = (c & 7) * 16;
      int j = j0 + j_in;
      int u = u_in ^ (j & 3);                 // pre-swizzled global source
      const u16* gp = Wpb + (size_t)j * CKP + kt * 32 + u * 8;
      GLOAD_LDS16(gp, &Bs[(size_t)(kt * 128 + j0) * 32]);
    }
  }

  f32x4 acc[2][8];
#pragma unroll
  for (int fr = 0; fr < 2; ++fr)
#pragma unroll
    for (int fc = 0; fc < 8; ++fc) {
      acc[fr][fc][0] = 0.f; acc[fr][fc][1] = 0.f;
      acc[fr][fc][2] = 0.f; acc[fr][fc][3] = 0.f;
    }

  const int frow = lane & 15, g = lane >> 4;
  const float* c0p = content + (size_t)(row0 + w * 32 + frow) * C;
  const float* c1p = c0p + (size_t)16 * C;

  auto loadA = [&](int kt) -> Afrag {
    Afrag r;
    int col = kt * 32 + g * 8;
    if (kt < NKT - 1) {
      r.x00 = *(const float4*)(c0p + col); r.x01 = *(const float4*)(c0p + col + 4);
      r.x10 = *(const float4*)(c1p + col); r.x11 = *(const float4*)(c1p + col + 4);
    } else {                                // K tail: cols 288..319, valid < 300
      float v0[8], v1[8];
#pragma unroll
      for (int i = 0; i < 8; ++i) {
        int cc = col + i;
        v0[i] = (cc < C) ? c0p[cc] : 0.f;
        v1[i] = (cc < C) ? c1p[cc] : 0.f;
      }
      r.x00 = make_float4(v0[0], v0[1], v0[2], v0[3]);
      r.x01 = make_float4(v0[4], v0[5], v0[6], v0[7]);
      r.x10 = make_float4(v1[0], v1[1], v1[2], v1[3]);
      r.x11 = make_float4(v1[4], v1[5], v1[6], v1[7]);
    }
    return r;
  };

  const int bsw = (g ^ (frow & 3)) * 8;
  auto compute = [&](const Afrag& a, int kt) {
    u16x8 a0v, a1v;
    a0v[0]=f2bf(a.x00.x); a0v[1]=f2bf(a.x00.y); a0v[2]=f2bf(a.x00.z); a0v[3]=f2bf(a.x00.w);
    a0v[4]=f2bf(a.x01.x); a0v[5]=f2bf(a.x01.y); a0v[6]=f2bf(a.x01.z); a0v[7]=f2bf(a.x01.w);
    a1v[0]=f2bf(a.x10.x); a1v[1]=f2bf(a.x10.y); a1v[2]=f2bf(a.x10.z); a1v[3]=f2bf(a.x10.w);
    a1v[4]=f2bf(a.x11.x); a1v[5]=f2bf(a.x11.y); a1v[6]=f2bf(a.x11.z); a1v[7]=f2bf(a.x11.w);
    short8 a0 = *(short8*)&a0v, a1 = *(short8*)&a1v;
#pragma unroll
    for (int fc = 0; fc < 8; ++fc) {
      short8 bfr = *(const short8*)&Bs[(size_t)(kt * 128 + fc * 16 + frow) * 32 + bsw];
      acc[0][fc] = __builtin_amdgcn_mfma_f32_16x16x32_bf16(a0, bfr, acc[0][fc], 0, 0, 0);
      acc[1][fc] = __builtin_amdgcn_mfma_f32_16x16x32_bf16(a1, bfr, acc[1][fc], 0, 0, 0);
    }
  };

  // distance-3 static register pipeline, zero in-loop barriers.
  // At compute(p) the awaited load was issued 3 compute-phases earlier;
  // 3 A-loads (12 dwordx4) stay in flight at every wait point.
  Afrag A0 = loadA(0);
  Afrag A1 = loadA(1);
  Afrag A2 = loadA(2);
  __syncthreads();                 // B resident from here on (drains prologue loads too)
  Afrag A3 = loadA(3); compute(A0, 0);
  A0 = loadA(4);       compute(A1, 1);
  A1 = loadA(5);       compute(A2, 2);
  A2 = loadA(6);       compute(A3, 3);
  A3 = loadA(7);       compute(A0, 4);
  A0 = loadA(8);       compute(A1, 5);
  A1 = loadA(9);       compute(A2, 6);
  compute(A3, 7);
  compute(A0, 8);
  compute(A1, 9);

  // ---- epilogue: bias + lrelu + emb gather, bf16 store ----
  float bpv[8];
#pragma unroll
  for (int fc = 0; fc < 8; ++fc) bpv[fc] = bp[fc * 16 + frow];
#pragma unroll
  for (int fr = 0; fr < 2; ++fr) {
#pragma unroll
    for (int q = 0; q < 4; ++q) {
      int n = row0 + w * 32 + fr * 16 + g * 4 + q;
      int gi = nid[n] + 1;
      const float* erow = emb + (size_t)gi * F;
      u16* orow = out + (size_t)n * ostride;
#pragma unroll
      for (int fc = 0; fc < 8; ++fc) {
        int col = fc * 16 + frow;
        float v = acc[fr][fc][q] + bpv[fc];
        orow[col] = f2bf(erow[col] + lrelu(v));
      }
    }
  }
}

// per dst d: xa = (sum_{src} hsrc[src] - h_self) / max(deg-1,1), bf16 into xcat[d][128:256]
__global__ __launch_bounds__(256) void gather_xa(
    const u16* __restrict__ hsrc, const int* __restrict__ csr,
    const int* __restrict__ deg, u16* __restrict__ xcat)
{
  int d = blockIdx.x * 4 + (threadIdx.x >> 6);
  int lane = threadIdx.x & 63;
  u32 hv = *(const u32*)&xcat[(size_t)d * (2 * F) + lane * 2];
  float h0f = bf2f((u16)(hv & 0xffff)), h1f = bf2f((u16)(hv >> 16));
  int dg = deg[d];
  int n = dg < CAP ? dg : CAP;
  const int* cp = csr + (size_t)d * CAP;
  float s0 = 0.f, s1 = 0.f;
  int j = 0;
  for (; j + 4 <= n; j += 4) {
    int i0 = cp[j], i1 = cp[j + 1], i2 = cp[j + 2], i3 = cp[j + 3];
    u32 v0 = *(const u32*)&hsrc[(size_t)i0 * F + lane * 2];
    u32 v1 = *(const u32*)&hsrc[(size_t)i1 * F + lane * 2];
    u32 v2 = *(const u32*)&hsrc[(size_t)i2 * F + lane * 2];
    u32 v3 = *(const u32*)&hsrc[(size_t)i3 * F + lane * 2];
    s0 += bf2f((u16)(v0 & 0xffff)) + bf2f((u16)(v1 & 0xffff))
        + bf2f((u16)(v2 & 0xffff)) + bf2f((u16)(v3 & 0xffff));
    s1 += bf2f((u16)(v0 >> 16)) + bf2f((u16)(v1 >> 16))
        + bf2f((u16)(v2 >> 16)) + bf2f((u16)(v3 >> 16));
  }
  for (; j < n; ++j) {
    u32 v = *(const u32*)&hsrc[(size_t)cp[j] * F + lane * 2];
    s0 += bf2f((u16)(v & 0xffff));
    s1 += bf2f((u16)(v >> 16));
  }
  float inv = 1.f / fmaxf((float)dg - 1.f, 1.f);
  u16 a0 = f2bf((s0 - h0f) * inv), a1 = f2bf((s1 - h1f) * inv);
  *(u32*)&xcat[(size_t)d * (2 * F) + F + lane * 2] = ((u32)a1 << 16) | a0;
}

// out[n] = normalize(lrelu(xcat[n,:] @ Wc.T + bc));  xcat bf16 [n][256]
template<int F32OUT>
__global__ __launch_bounds__(256) void conv_mfma(
    const u16* __restrict__ xcat, const u16* __restrict__ Wcb,
    const float* __restrict__ bc, u16* __restrict__ outb,
    float* __restrict__ outf)
{
  __shared__ u16 As[128][LDA];
  __shared__ u16 Bs[128][LDA];
  const int t = threadIdx.x;
  const int lane = t & 63, w = t >> 6;
  const int row0 = blockIdx.x * 128;

  f32x4 acc[2][8];
#pragma unroll
  for (int fr = 0; fr < 2; ++fr)
#pragma unroll
    for (int fc = 0; fc < 8; ++fc) {
      acc[fr][fc][0] = 0.f; acc[fr][fc][1] = 0.f;
      acc[fr][fc][2] = 0.f; acc[fr][fc][3] = 0.f;
    }

  for (int k0 = 0; k0 < K2F; k0 += 32) {
    if (k0) __syncthreads();
#pragma unroll
    for (int it = 0; it < 2; ++it) {
      int cc = it * 256 + t;
      int r = cc >> 2, kc = (cc & 3) * 8;
      *(u16x8*)&As[r][kc] = *(const u16x8*)&xcat[(size_t)(row0 + r) * K2F + k0 + kc];
      *(u16x8*)&Bs[r][kc] = *(const u16x8*)&Wcb[(size_t)r * K2F + k0 + kc];
    }
    __syncthreads();

    const int frow = lane & 15;
    const int kc = (lane >> 4) * 8;
    short8 a0 = *(const short8*)&As[w * 32 + frow][kc];
    short8 a1 = *(const short8*)&As[w * 32 + 16 + frow][kc];
#pragma unroll
    for (int fc = 0; fc < 8; ++fc) {
      short8 b = *(const short8*)&Bs[fc * 16 + frow][kc];
      acc[0][fc] = __builtin_amdgcn_mfma_f32_16x16x32_bf16(a0, b, acc[0][fc], 0, 0, 0);
      acc[1][fc] = __builtin_amdgcn_mfma_f32_16x16x32_bf16(a1, b, acc[1][fc], 0, 0, 0);
    }
  }

  float bcv[8];
#pragma unroll
  for (int fc = 0; fc < 8; ++fc) bcv[fc] = bc[fc * 16 + (lane & 15)];
#pragma unroll
  for (int fr = 0; fr < 2; ++fr) {
#pragma unroll
    for (int q = 0; q < 4; ++q) {
      float x[8];
      float ss = 0.f;
#pragma unroll
      for (int fc = 0; fc < 8; ++fc) {
        x[fc] = lrelu(acc[fr][fc][q] + bcv[fc]);
        ss += x[fc] * x[fc];
      }
#pragma unroll
      for (int m = 8; m >= 1; m >>= 1) ss += __shfl_xor(ss, m, 64);
      float nrm = 1.f / fmaxf(sqrtf(ss), 1e-6f);
      int n = row0 + w * 32 + fr * 16 + (lane >> 4) * 4 + q;
#pragma unroll
      for (int fc = 0; fc < 8; ++fc) {
        int col = fc * 16 + (lane & 15);
        if (F32OUT) outf[(size_t)n * F + col] = x[fc] * nrm;
        else        outb[(size_t)n * F + col] = f2bf(x[fc] * nrm);
      }
    }
  }
}

extern "C" void kernel_launch(void* const* d_in, const int* in_sizes, int n_in,
                              void* d_out, int out_size, void* d_ws, size_t ws_size,
                              hipStream_t stream) {
  const int*   nid0     = (const int*)d_in[0];
  const int*   nid1     = (const int*)d_in[1];
  const int*   nid2     = (const int*)d_in[2];
  const float* content0 = (const float*)d_in[3];
  const float* content1 = (const float*)d_in[4];
  const float* content2 = (const float*)d_in[5];
  const int*   b0s      = (const int*)d_in[6];
  const int*   b0d      = (const int*)d_in[7];
  const int*   b1s      = (const int*)d_in[8];
  const int*   b1d      = (const int*)d_in[9];
  const float* emb      = (const float*)d_in[10];
  const float* Wp0      = (const float*)d_in[11];
  const float* bp0      = (const float*)d_in[12];
  const float* Wp1      = (const float*)d_in[13];
  const float* bp1      = (const float*)d_in[14];
  const float* Wp2      = (const float*)d_in[15];
  const float* bp2      = (const float*)d_in[16];
  const float* Wc0      = (const float*)d_in[17];
  const float* bc0      = (const float*)d_in[18];
  const float* Wc1      = (const float*)d_in[19];
  const float* bc1      = (const float*)d_in[20];

  u16* wsu = (u16*)d_ws;
  u16* h0b   = wsu;                               // N0*F bf16
  u16* xcat1 = h0b + (size_t)N0_ * F;             // N1*256 bf16 (h1 | xa1)
  u16* xcat2 = xcat1 + (size_t)N1_ * 2 * F;       // N2*256 bf16 (h2 | xa2)
  u16* h1nb  = xcat2 + (size_t)N2_ * 2 * F;       // N1*F bf16 (conv0 out)
  u16* Wpb0  = h1nb + (size_t)N1_ * F;            // F*CKP bf16 each
  u16* Wpb1  = Wpb0 + (size_t)F * CKP;
  u16* Wpb2  = Wpb1 + (size_t)F * CKP;
  u16* Wcb0  = Wpb2 + (size_t)F * CKP;            // F*K2F bf16 each
  u16* Wcb1  = Wcb0 + (size_t)F * K2F;
  int* deg0  = (int*)(Wcb1 + (size_t)F * K2F);    // N1 } zeroed together
  int* deg1  = deg0 + N1_;                        // N2 }
  int* csr0  = deg1 + N2_;                        // N1*CAP
  int* csr1  = csr0 + (size_t)N1_ * CAP;          // N2*CAP

  // zero deg0|deg1 (contiguous, 16B-aligned)
  const int zn4 = (N1_ + N2_) / 4;
  zero_kernel<<<(zn4 + 255) / 256, 256, 0, stream>>>((float4*)deg0, zn4);

  build_csr<<<(E0_ + E1_ + 255) / 256, 256, 0, stream>>>(
      b0s, b0d, b1s, b1d, deg0, deg1, csr0, csr1);

  convert_all<<<(3 * F * CKP + 2 * F * K2F + 255) / 256, 256, 0, stream>>>(
      Wp0, Wp1, Wp2, Wc0, Wc1, Wpb0, Wpb1, Wpb2, Wcb0, Wcb1);

  embed_all<<<(N0_ + N1_ + N2_) / 128, 256, 0, stream>>>(
      content0, content1, content2, Wpb0, Wpb1, Wpb2,
      bp0, bp1, bp2, nid0, nid1, nid2, emb, h0b, xcat1, xcat2);

  gather_xa<<<N1_ / 4, 256, 0, stream>>>(h0b, csr0, deg0, xcat1);
  conv_mfma<0><<<N1_ / 128, 256, 0, stream>>>(xcat1, Wcb0, bc0, h1nb, nullptr);

  gather_xa<<<N2_ / 4, 256, 0, stream>>>(h1nb, csr1, deg1, xcat2);
  conv_mfma<1><<<N2_ / 128, 256, 0, stream>>>(xcat2, Wcb1, bc1, nullptr, (float*)d_out);
}